// Round 6
// baseline (587.355 us; speedup 1.0000x reference)
//
#include <hip/hip_runtime.h>
#include <math.h>

#define HC 256      // H*C
#define NHEAD 4
#define NEG_SLOPE 0.2f
#define GG 64       // graphs

typedef unsigned short u16;
typedef unsigned int u32;
typedef __attribute__((ext_vector_type(8))) short short8;
typedef __attribute__((ext_vector_type(4))) float f32x4;

static __device__ inline u16 f2bf_rn(float f) {
  u32 x = __float_as_uint(f);
  u32 r = (x + 0x7fffu + ((x >> 16) & 1u)) >> 16;
  return (u16)r;
}
static __device__ inline float bf2f(u16 u) { return __uint_as_float(((u32)u) << 16); }

// ---------------- CSR build ----------------

__global__ void count_deg_kernel(const int* __restrict__ ei, int E, int Nn, int* __restrict__ deg) {
  int idx = blockIdx.x * 256 + threadIdx.x;
  int Et = E + Nn;
  if (idx >= Et) return;
  int d = (idx < E) ? ei[E + idx] : (idx - E);   // row1 of edge_index = dst; self loops appended
  atomicAdd(&deg[d], 1);
}

__global__ void scan_partial_kernel(const int* __restrict__ deg, int Nn,
                                    int* __restrict__ rowptr, int* __restrict__ bsum) {
  __shared__ int s[256];
  int t = threadIdx.x, i = blockIdx.x * 256 + t;
  int v = (i < Nn) ? deg[i] : 0;
  s[t] = v; __syncthreads();
  for (int off = 1; off < 256; off <<= 1) {
    int x = (t >= off) ? s[t - off] : 0; __syncthreads();
    s[t] += x; __syncthreads();
  }
  if (i < Nn) rowptr[i] = s[t] - v;          // exclusive within block
  if (t == 255) bsum[blockIdx.x] = s[t];     // block total
}

__global__ void scan_bsum_kernel(int* __restrict__ bsum, int nb) {
  __shared__ int s[512];
  int t = threadIdx.x;
  int v = (t < nb) ? bsum[t] : 0;
  s[t] = v; __syncthreads();
  for (int off = 1; off < 512; off <<= 1) {
    int x = (t >= off) ? s[t - off] : 0; __syncthreads();
    s[t] += x; __syncthreads();
  }
  if (t < nb) bsum[t] = s[t] - v;            // exclusive block offsets
}

__global__ void scan_add_kernel(int* __restrict__ rowptr, const int* __restrict__ bsum,
                                int Nn, int Etot) {
  int i = blockIdx.x * 256 + threadIdx.x;
  if (i < Nn) rowptr[i] += bsum[blockIdx.x];
  if (i == 0) rowptr[Nn] = Etot;
}

__global__ void fill_csr_kernel(const int* __restrict__ ei, int E, int Nn,
                                const int* __restrict__ rowptr, int* __restrict__ cursor,
                                int* __restrict__ col) {
  int idx = blockIdx.x * 256 + threadIdx.x;
  int Et = E + Nn;
  if (idx >= Et) return;
  int s, d;
  if (idx < E) { s = ei[idx]; d = ei[E + idx]; } else { s = d = idx - E; }
  int pos = atomicAdd(&cursor[d], 1);
  col[rowptr[d] + pos] = s;
}

// ---------------- W transpose + hi/lo bf16 split: Wt[n][k] ----------------

__global__ void convert_w_kernel(const float* __restrict__ W, u16* __restrict__ hi,
                                 u16* __restrict__ lo) {
  int idx = blockIdx.x * 256 + threadIdx.x;    // 65536 threads
  if (idx >= 256 * 256) return;
  int k = idx >> 8, n = idx & 255;             // coalesced read of W[k][n]
  float v = W[idx];
  u16 h = f2bf_rn(v);
  u16 l = f2bf_rn(v - bf2f(h));
  hi[n * 256 + k] = h;
  lo[n * 256 + k] = l;
}

// ---------------- layer 1: K=2 GEMM fused with attention logits ----------------
// wave per node; h written as bf16 (message path); logits from fp32 values.

__global__ __launch_bounds__(256) void gemm_k2_logits_kernel(
    const float* __restrict__ x, const float* __restrict__ W,
    const float* __restrict__ as_, const float* __restrict__ ad_,
    u16* __restrict__ h16, float* __restrict__ als, float* __restrict__ ald, int Nn) {
  int node = blockIdx.x * 4 + (threadIdx.x >> 6);
  int lane = threadIdx.x & 63;
  if (node >= Nn) return;
  float x0 = x[node * 2], x1 = x[node * 2 + 1];
  float ps[4], pd[4];
  #pragma unroll
  for (int q = 0; q < 4; ++q) {
    int c = q * 64 + lane;
    float o = x0 * W[c] + x1 * W[256 + c];
    h16[(size_t)node * HC + c] = f2bf_rn(o);
    ps[q] = o * as_[c];
    pd[q] = o * ad_[c];
  }
  #pragma unroll
  for (int off = 32; off >= 1; off >>= 1) {
    #pragma unroll
    for (int q = 0; q < 4; ++q) {
      ps[q] += __shfl_xor(ps[q], off, 64);
      pd[q] += __shfl_xor(pd[q], off, 64);
    }
  }
  if (lane == 0) {
    *(float4*)&als[node * 4] = make_float4(ps[0], ps[1], ps[2], ps[3]);
    *(float4*)&ald[node * 4] = make_float4(pd[0], pd[1], pd[2], pd[3]);
  }
}

// ---------------- LDS-free bf16-A x split-bf16-W MFMA GEMM + fused logits ----------------
// A bf16 [M][256]; B transposed hi/lo bf16 Wt[n][k] (L2-resident, re-read freely).
// No LDS, no barriers: each wave loads its own MFMA fragments straight from
// global (per-lane 16B dwordx4). K fully unrolled; latency hidden by TLP.
// C = A@Whi + A@Wlo (exact W); C written bf16; logits from fp32 acc (head=bc*2+wc).

#define GBM 128
#define GBN 128

__global__ __launch_bounds__(256) void gemm_mfma_kernel(
    const u16* __restrict__ A,
    const u16* __restrict__ Bhi, const u16* __restrict__ Blo,
    const float* __restrict__ as_, const float* __restrict__ ad_,
    u16* __restrict__ C16, float* __restrict__ als, float* __restrict__ ald, int Mrows) {
  int bc = blockIdx.x, br = blockIdx.y;
  int tid = threadIdx.x;
  int wid = tid >> 6, lane = tid & 63;
  int wr = wid >> 1, wc = wid & 1;             // 2x2 wave grid, 64x64 per wave
  int row0 = br * GBM, col0 = bc * GBN;
  int fr = lane & 15, fg = lane >> 4;

  const u16* ap[4];
  const u16* bhp[4];
  const u16* blp[4];
  #pragma unroll
  for (int m = 0; m < 4; ++m) {
    int r = row0 + wr * 64 + m * 16 + fr;
    if (r >= Mrows) r = Mrows - 1;
    ap[m] = A + (size_t)r * 256 + fg * 8;
  }
  #pragma unroll
  for (int n = 0; n < 4; ++n) {
    int c = col0 + wc * 64 + n * 16 + fr;
    bhp[n] = Bhi + (size_t)c * 256 + fg * 8;
    blp[n] = Blo + (size_t)c * 256 + fg * 8;
  }

  f32x4 acc[4][4];
  #pragma unroll
  for (int m = 0; m < 4; ++m)
    #pragma unroll
    for (int n = 0; n < 4; ++n) acc[m][n] = (f32x4){0.f, 0.f, 0.f, 0.f};

  #pragma unroll
  for (int ks = 0; ks < 8; ++ks) {             // K = 8 x 32
    short8 a[4], bh[4], bl[4];
    #pragma unroll
    for (int m = 0; m < 4; ++m) a[m] = *(const short8*)(ap[m] + ks * 32);
    #pragma unroll
    for (int n = 0; n < 4; ++n) {
      bh[n] = *(const short8*)(bhp[n] + ks * 32);
      bl[n] = *(const short8*)(blp[n] + ks * 32);
    }
    #pragma unroll
    for (int m = 0; m < 4; ++m)
      #pragma unroll
      for (int n = 0; n < 4; ++n) {
        acc[m][n] = __builtin_amdgcn_mfma_f32_16x16x32_bf16(a[m], bh[n], acc[m][n], 0, 0, 0);
        acc[m][n] = __builtin_amdgcn_mfma_f32_16x16x32_bf16(a[m], bl[n], acc[m][n], 0, 0, 0);
      }
  }

  // C write (bf16): col=lane&15 within frag, row=(lane>>4)*4+j
  #pragma unroll
  for (int m = 0; m < 4; ++m) {
    #pragma unroll
    for (int n = 0; n < 4; ++n) {
      int col = col0 + wc * 64 + n * 16 + fr;
      #pragma unroll
      for (int j = 0; j < 4; ++j) {
        int row = row0 + wr * 64 + m * 16 + fg * 4 + j;
        if (row < Mrows) C16[(size_t)row * 256 + col] = f2bf_rn(acc[m][n][j]);
      }
    }
  }

  // fused logits: this wave's cols = one head
  int head = bc * 2 + wc;
  float asv[4], adv[4];
  #pragma unroll
  for (int n = 0; n < 4; ++n) {
    asv[n] = as_[head * 64 + n * 16 + fr];
    adv[n] = ad_[head * 64 + n * 16 + fr];
  }
  #pragma unroll
  for (int m = 0; m < 4; ++m) {
    #pragma unroll
    for (int j = 0; j < 4; ++j) {
      float ps = 0.f, pd = 0.f;
      #pragma unroll
      for (int n = 0; n < 4; ++n) {
        ps += acc[m][n][j] * asv[n];
        pd += acc[m][n][j] * adv[n];
      }
      #pragma unroll
      for (int off = 1; off < 16; off <<= 1) {
        ps += __shfl_xor(ps, off, 64);
        pd += __shfl_xor(pd, off, 64);
      }
      int grow = row0 + wr * 64 + m * 16 + fg * 4 + j;
      if (fr == 0 && grow < Mrows) {
        als[grow * 4 + head] = ps;
        ald[grow * 4 + head] = pd;
      }
    }
  }
}

// ---------------- edge softmax: per-edge normalized weights (thread per node) ----------------

__global__ void edge_softmax_kernel(const float* __restrict__ als, const float* __restrict__ ald,
                                    const int* __restrict__ rowptr, const int* __restrict__ col,
                                    float* __restrict__ w, float* __restrict__ invS, int Nn) {
  int node = blockIdx.x * 256 + threadIdx.x;
  if (node >= Nn) return;
  int rs = rowptr[node], re = rowptr[node + 1];
  float4 ad = *(const float4*)&ald[node * 4];
  float m0 = -INFINITY, m1 = -INFINITY, m2 = -INFINITY, m3 = -INFINITY;
  for (int i = rs; i < re; ++i) {
    int s = col[i];
    float4 a = *(const float4*)&als[(size_t)s * 4];
    float e0 = a.x + ad.x; e0 = e0 > 0.f ? e0 : NEG_SLOPE * e0;
    float e1 = a.y + ad.y; e1 = e1 > 0.f ? e1 : NEG_SLOPE * e1;
    float e2 = a.z + ad.z; e2 = e2 > 0.f ? e2 : NEG_SLOPE * e2;
    float e3 = a.w + ad.w; e3 = e3 > 0.f ? e3 : NEG_SLOPE * e3;
    *(float4*)&w[(size_t)i * 4] = make_float4(e0, e1, e2, e3);
    m0 = fmaxf(m0, e0); m1 = fmaxf(m1, e1); m2 = fmaxf(m2, e2); m3 = fmaxf(m3, e3);
  }
  float S0 = 0.f, S1 = 0.f, S2 = 0.f, S3 = 0.f;
  for (int i = rs; i < re; ++i) {
    float4 e = *(const float4*)&w[(size_t)i * 4];
    float p0 = __expf(e.x - m0), p1 = __expf(e.y - m1);
    float p2 = __expf(e.z - m2), p3 = __expf(e.w - m3);
    S0 += p0; S1 += p1; S2 += p2; S3 += p3;
    *(float4*)&w[(size_t)i * 4] = make_float4(p0, p1, p2, p3);
  }
  *(float4*)&invS[node * 4] = make_float4(1.f / (S0 + 1e-16f), 1.f / (S1 + 1e-16f),
                                          1.f / (S2 + 1e-16f), 1.f / (S3 + 1e-16f));
}

// ---------------- GAT gather v3: weighted sum, channel-pair dwords ----------------
// wave per node (scalarized); lane owns channels {2l, 2l+1, 128+2l, 128+2l+1}.
// Per edge: uniform col + uniform float4 w + 2 per-lane dword loads + 4 FMA.
// Output: bf16 packed u32 stores (feeds next GEMM's bf16 A, or the pool).

__global__ __launch_bounds__(256) void gat_gather_kernel(const u16* __restrict__ h16,
    const float* __restrict__ w, const float* __restrict__ invS,
    const int* __restrict__ rowptr, const int* __restrict__ col,
    const float* __restrict__ bias, u16* __restrict__ out16, int Nn) {
  int node = __builtin_amdgcn_readfirstlane(blockIdx.x * 4 + (threadIdx.x >> 6));
  int lane = threadIdx.x & 63;
  if (node >= Nn) return;
  int rs = rowptr[node], re = rowptr[node + 1];
  int hsel = lane >> 5;                       // head parity selector
  float a0 = 0.f, a1 = 0.f, a2 = 0.f, a3 = 0.f;
  const u32* h32 = (const u32*)h16;
  for (int i = rs; i < re; ++i) {
    int s = col[i];
    float4 wv = *(const float4*)&w[(size_t)i * 4];
    float wA = hsel ? wv.y : wv.x;
    float wB = hsel ? wv.w : wv.z;
    const u32* hr = h32 + (size_t)s * 128;
    u32 pa = hr[lane];                        // ch 2l, 2l+1   (head l>>5)
    u32 pb = hr[64 + lane];                   // ch 128+2l, 128+2l+1 (head 2+(l>>5))
    a0 += wA * __uint_as_float(pa << 16);
    a1 += wA * __uint_as_float(pa & 0xffff0000u);
    a2 += wB * __uint_as_float(pb << 16);
    a3 += wB * __uint_as_float(pb & 0xffff0000u);
  }
  float4 iS = *(const float4*)&invS[node * 4];
  float isA = hsel ? iS.y : iS.x;
  float isB = hsel ? iS.w : iS.z;
  float2 bA = *(const float2*)&bias[2 * lane];
  float2 bB = *(const float2*)&bias[128 + 2 * lane];
  float o0 = a0 * isA + bA.x;
  float o1 = a1 * isA + bA.y;
  float o2 = a2 * isB + bB.x;
  float o3 = a3 * isB + bB.y;
  o0 = o0 > 0.f ? o0 : (__expf(o0) - 1.0f);   // ELU (alpha=1)
  o1 = o1 > 0.f ? o1 : (__expf(o1) - 1.0f);
  o2 = o2 > 0.f ? o2 : (__expf(o2) - 1.0f);
  o3 = o3 > 0.f ? o3 : (__expf(o3) - 1.0f);
  u32* o32 = (u32*)out16;
  o32[(size_t)node * 128 + lane]      = (u32)f2bf_rn(o0) | ((u32)f2bf_rn(o1) << 16);
  o32[(size_t)node * 128 + 64 + lane] = (u32)f2bf_rn(o2) | ((u32)f2bf_rn(o3) << 16);
}

// ---------------- pooling + MLP ----------------

__global__ void bounds_kernel(const int* __restrict__ batch, int Nn, int* __restrict__ bounds) {
  int g = threadIdx.x;
  if (g > GG) return;
  int lo = 0, hi = Nn;
  while (lo < hi) { int mid = (lo + hi) >> 1; if (batch[mid] < g) lo = mid + 1; else hi = mid; }
  bounds[g] = lo;   // lower_bound of g; bounds[64] = N
}

__global__ void pool_kernel(const u16* __restrict__ X, const int* __restrict__ bounds,
                            float* __restrict__ pooled) {
  int g = blockIdx.x, split = blockIdx.y, t = threadIdx.x;
  int s = bounds[g], e = bounds[g + 1];
  int cnt = e - s;
  if (cnt <= 0) return;
  int chunk = (cnt + gridDim.y - 1) / gridDim.y;
  int s2 = s + split * chunk, e2 = min(e, s2 + chunk);
  if (s2 >= e2) return;
  float sum = 0.f;
  for (int n = s2; n < e2; ++n) sum += bf2f(X[(size_t)n * HC + t]);
  atomicAdd(&pooled[g * HC + t], sum);
}

__global__ __launch_bounds__(512) void mlp_kernel(const float* __restrict__ pooled,
    const int* __restrict__ bounds, const float* __restrict__ Wp1, const float* __restrict__ bp1,
    const float* __restrict__ Wp2, const float* __restrict__ bp2, float* __restrict__ out) {
  __shared__ float p[256];
  __shared__ float z1[512];
  int g = blockIdx.x, t = threadIdx.x;
  if (t < 256) {
    int cnt = bounds[g + 1] - bounds[g];
    float inv = 1.0f / (float)(cnt > 1 ? cnt : 1);
    p[t] = pooled[g * 256 + t] * inv;
  }
  __syncthreads();
  float a1 = bp1[t];
  for (int k = 0; k < 256; ++k) a1 += p[k] * Wp1[k * 512 + t];
  z1[t] = fmaxf(a1, 0.f);
  __syncthreads();
  if (t < 256) {
    float a2 = bp2[t];
    for (int k = 0; k < 512; ++k) a2 += z1[k] * Wp2[k * 256 + t];
    out[g * 256 + t] = a2;
  }
}

// ---------------- launch ----------------

static inline size_t align_up(size_t x, size_t a) { return (x + a - 1) & ~(a - 1); }

extern "C" void kernel_launch(void* const* d_in, const int* in_sizes, int n_in,
                              void* d_out, int out_size, void* d_ws, size_t ws_size,
                              hipStream_t stream) {
  const float* x    = (const float*)d_in[0];
  const int*   ei   = (const int*)d_in[1];
  const int*   batch= (const int*)d_in[2];
  const float* W1   = (const float*)d_in[3];
  const float* a1s  = (const float*)d_in[4];
  const float* a1d  = (const float*)d_in[5];
  const float* b1   = (const float*)d_in[6];
  const float* W2   = (const float*)d_in[7];
  const float* a2s  = (const float*)d_in[8];
  const float* a2d  = (const float*)d_in[9];
  const float* b2   = (const float*)d_in[10];
  const float* W3   = (const float*)d_in[11];
  const float* a3s  = (const float*)d_in[12];
  const float* a3d  = (const float*)d_in[13];
  const float* b3   = (const float*)d_in[14];
  const float* Wp1  = (const float*)d_in[15];
  const float* bp1  = (const float*)d_in[16];
  const float* Wp2  = (const float*)d_in[17];
  const float* bp2  = (const float*)d_in[18];

  const int N = in_sizes[0] / 2;       // 100000
  const int E = in_sizes[1] / 2;       // 400000
  const int Et = E + N;                // with self loops

  char* base = (char*)d_ws;
  size_t off = 0;
  auto alloc = [&](size_t bytes) { size_t o = off; off = align_up(off + bytes, 256); return o; };
  u16*   h16    = (u16*)  (base + alloc((size_t)N * HC * 2));   // message-path h (bf16)
  u16*   xhi    = (u16*)  (base + alloc((size_t)N * HC * 2));   // gather out (bf16)
  float* als    = (float*)(base + alloc((size_t)N * 4 * 4));
  float* ald    = (float*)(base + alloc((size_t)N * 4 * 4));
  float* invS   = (float*)(base + alloc((size_t)N * 4 * 4));
  int*   rowptr = (int*)  (base + alloc((size_t)(N + 1) * 4));
  int*   col    = (int*)  (base + alloc((size_t)Et * 4));
  float* w      = (float*)(base + alloc((size_t)Et * 4 * 4));   // per-edge softmax numerators
  int*   deg    = (int*)  (base + alloc((size_t)N * 4));
  int*   cursor = (int*)  (base + alloc((size_t)N * 4));
  int*   bsum   = (int*)  (base + alloc(512 * 4));
  int*   bounds = (int*)  (base + alloc((GG + 1) * 4));
  float* pooled = (float*)(base + alloc((size_t)GG * HC * 4));
  (void)ws_size; (void)n_in; (void)out_size;

  // W2t/W3t hi/lo parked in deg/cursor space (dead after CSR build; 400 KB >= 256 KB)
  u16* W2thi = (u16*)deg;    u16* W2tlo = W2thi + 256 * 256;
  u16* W3thi = (u16*)cursor; u16* W3tlo = W3thi + 256 * 256;

  hipMemsetAsync(deg, 0, (size_t)N * 4, stream);
  hipMemsetAsync(cursor, 0, (size_t)N * 4, stream);
  hipMemsetAsync(pooled, 0, (size_t)GG * HC * 4, stream);

  // CSR by destination (same edge set for all layers)
  int ebk = (Et + 255) / 256;
  count_deg_kernel<<<ebk, 256, 0, stream>>>(ei, E, N, deg);
  int NT = (N + 255) / 256;
  scan_partial_kernel<<<NT, 256, 0, stream>>>(deg, N, rowptr, bsum);
  scan_bsum_kernel<<<1, 512, 0, stream>>>(bsum, NT);
  scan_add_kernel<<<NT, 256, 0, stream>>>(rowptr, bsum, N, Et);
  fill_csr_kernel<<<ebk, 256, 0, stream>>>(ei, E, N, rowptr, cursor, col);

  // weight conversion (deg/cursor now dead)
  convert_w_kernel<<<256, 256, 0, stream>>>(W2, W2thi, W2tlo);
  convert_w_kernel<<<256, 256, 0, stream>>>(W3, W3thi, W3tlo);

  dim3 gemm_grid(HC / GBN, (N + GBM - 1) / GBM);
  int nodeblk = (N + 3) / 4;

  // layer 1 (in=2, logits fused)
  gemm_k2_logits_kernel<<<nodeblk, 256, 0, stream>>>(x, W1, a1s, a1d, h16, als, ald, N);
  edge_softmax_kernel<<<NT, 256, 0, stream>>>(als, ald, rowptr, col, w, invS, N);
  gat_gather_kernel<<<nodeblk, 256, 0, stream>>>(h16, w, invS, rowptr, col, b1, xhi, N);
  // layer 2
  gemm_mfma_kernel<<<gemm_grid, 256, 0, stream>>>(xhi, W2thi, W2tlo, a2s, a2d,
                                                  h16, als, ald, N);
  edge_softmax_kernel<<<NT, 256, 0, stream>>>(als, ald, rowptr, col, w, invS, N);
  gat_gather_kernel<<<nodeblk, 256, 0, stream>>>(h16, w, invS, rowptr, col, b2, xhi, N);
  // layer 3
  gemm_mfma_kernel<<<gemm_grid, 256, 0, stream>>>(xhi, W3thi, W3tlo, a3s, a3d,
                                                  h16, als, ald, N);
  edge_softmax_kernel<<<NT, 256, 0, stream>>>(als, ald, rowptr, col, w, invS, N);
  gat_gather_kernel<<<nodeblk, 256, 0, stream>>>(h16, w, invS, rowptr, col, b3, xhi, N);

  // pool + MLP
  bounds_kernel<<<1, 128, 0, stream>>>(batch, N, bounds);
  pool_kernel<<<dim3(GG, 8), 256, 0, stream>>>(xhi, bounds, pooled);
  mlp_kernel<<<GG, 512, 0, stream>>>(pooled, bounds, Wp1, bp1, Wp2, bp2, (float*)d_out);
}

// Round 7
// 559.654 us; speedup vs baseline: 1.0495x; 1.0495x over previous
//
#include <hip/hip_runtime.h>
#include <math.h>

#define HC 256      // H*C
#define NHEAD 4
#define NEG_SLOPE 0.2f
#define GG 64       // graphs

typedef unsigned short u16;
typedef unsigned int u32;
typedef __attribute__((ext_vector_type(8))) short short8;
typedef __attribute__((ext_vector_type(4))) float f32x4;

static __device__ inline u16 f2bf_rn(float f) {
  u32 x = __float_as_uint(f);
  u32 r = (x + 0x7fffu + ((x >> 16) & 1u)) >> 16;
  return (u16)r;
}
static __device__ inline float bf2f(u16 u) { return __uint_as_float(((u32)u) << 16); }

// ---------------- CSR build ----------------

__global__ void count_deg_kernel(const int* __restrict__ ei, int E, int Nn, int* __restrict__ deg) {
  int idx = blockIdx.x * 256 + threadIdx.x;
  int Et = E + Nn;
  if (idx >= Et) return;
  int d = (idx < E) ? ei[E + idx] : (idx - E);   // row1 of edge_index = dst; self loops appended
  atomicAdd(&deg[d], 1);
}

__global__ void scan_partial_kernel(const int* __restrict__ deg, int Nn,
                                    int* __restrict__ rowptr, int* __restrict__ bsum) {
  __shared__ int s[256];
  int t = threadIdx.x, i = blockIdx.x * 256 + t;
  int v = (i < Nn) ? deg[i] : 0;
  s[t] = v; __syncthreads();
  for (int off = 1; off < 256; off <<= 1) {
    int x = (t >= off) ? s[t - off] : 0; __syncthreads();
    s[t] += x; __syncthreads();
  }
  if (i < Nn) rowptr[i] = s[t] - v;          // exclusive within block
  if (t == 255) bsum[blockIdx.x] = s[t];     // block total
}

__global__ void scan_bsum_kernel(int* __restrict__ bsum, int nb) {
  __shared__ int s[512];
  int t = threadIdx.x;
  int v = (t < nb) ? bsum[t] : 0;
  s[t] = v; __syncthreads();
  for (int off = 1; off < 512; off <<= 1) {
    int x = (t >= off) ? s[t - off] : 0; __syncthreads();
    s[t] += x; __syncthreads();
  }
  if (t < nb) bsum[t] = s[t] - v;            // exclusive block offsets
}

__global__ void scan_add_kernel(int* __restrict__ rowptr, const int* __restrict__ bsum,
                                int Nn, int Etot) {
  int i = blockIdx.x * 256 + threadIdx.x;
  if (i < Nn) rowptr[i] += bsum[blockIdx.x];
  if (i == 0) rowptr[Nn] = Etot;
}

__global__ void fill_csr_kernel(const int* __restrict__ ei, int E, int Nn,
                                const int* __restrict__ rowptr, int* __restrict__ cursor,
                                int* __restrict__ col) {
  int idx = blockIdx.x * 256 + threadIdx.x;
  int Et = E + Nn;
  if (idx >= Et) return;
  int s, d;
  if (idx < E) { s = ei[idx]; d = ei[E + idx]; } else { s = d = idx - E; }
  int pos = atomicAdd(&cursor[d], 1);
  col[rowptr[d] + pos] = s;
}

// ---------------- W transpose + hi/lo bf16 split: Wt[n][k] ----------------

__global__ void convert_w_kernel(const float* __restrict__ W, u16* __restrict__ hi,
                                 u16* __restrict__ lo) {
  int idx = blockIdx.x * 256 + threadIdx.x;    // 65536 threads
  if (idx >= 256 * 256) return;
  int k = idx >> 8, n = idx & 255;             // coalesced read of W[k][n]
  float v = W[idx];
  u16 h = f2bf_rn(v);
  u16 l = f2bf_rn(v - bf2f(h));
  hi[n * 256 + k] = h;
  lo[n * 256 + k] = l;
}

// ---------------- layer 1: K=2 GEMM fused with attention logits ----------------
// wave per node; h written as bf16 (message path); logits from fp32 values.

__global__ __launch_bounds__(256) void gemm_k2_logits_kernel(
    const float* __restrict__ x, const float* __restrict__ W,
    const float* __restrict__ as_, const float* __restrict__ ad_,
    u16* __restrict__ h16, float* __restrict__ als, float* __restrict__ ald, int Nn) {
  int node = blockIdx.x * 4 + (threadIdx.x >> 6);
  int lane = threadIdx.x & 63;
  if (node >= Nn) return;
  float x0 = x[node * 2], x1 = x[node * 2 + 1];
  float ps[4], pd[4];
  #pragma unroll
  for (int q = 0; q < 4; ++q) {
    int c = q * 64 + lane;
    float o = x0 * W[c] + x1 * W[256 + c];
    h16[(size_t)node * HC + c] = f2bf_rn(o);
    ps[q] = o * as_[c];
    pd[q] = o * ad_[c];
  }
  #pragma unroll
  for (int off = 32; off >= 1; off >>= 1) {
    #pragma unroll
    for (int q = 0; q < 4; ++q) {
      ps[q] += __shfl_xor(ps[q], off, 64);
      pd[q] += __shfl_xor(pd[q], off, 64);
    }
  }
  if (lane == 0) {
    *(float4*)&als[node * 4] = make_float4(ps[0], ps[1], ps[2], ps[3]);
    *(float4*)&ald[node * 4] = make_float4(pd[0], pd[1], pd[2], pd[3]);
  }
}

// ---------------- full-K LDS-panel MFMA GEMM + fused logits ----------------
// A bf16 [M][256] staged ONCE per block into a 64KB LDS panel with fully
// contiguous global reads (fixes HBM 64B-scatter inefficiency). B = W hi/lo
// planes read per-lane from global (256KB, L2-resident). BN=256 (full width):
// A and C each touch HBM exactly once. One barrier total; K-loop barrier-free.
// XOR slot swizzle (slot ^= row&7) -> 2-way LDS aliasing only (free).
// C = A@Whi + A@Wlo (exact W); C written bf16; logits from fp32 acc.

#define GBM 128

__global__ __launch_bounds__(256, 2) void gemm_mfma_kernel(
    const u16* __restrict__ A,
    const u16* __restrict__ Bhi, const u16* __restrict__ Blo,
    const float* __restrict__ as_, const float* __restrict__ ad_,
    u16* __restrict__ C16, float* __restrict__ als, float* __restrict__ ald, int Mrows) {
  __shared__ __align__(16) u16 As[GBM * 256];   // 64KB, 16B slots, swizzled
  int br = blockIdx.x;
  int tid = threadIdx.x;
  int wid = tid >> 6, lane = tid & 63;
  int wr = wid >> 1, wc = wid & 1;             // 2x2 waves; each 64 rows x 128 cols
  int row0 = br * GBM;
  int fr = lane & 15, fg = lane >> 4;

  // stage A panel: 4096 slots x 16B; slot s: row=s>>5, c=s&31; src col-slot = c^(row&7)
  #pragma unroll
  for (int p = 0; p < 16; ++p) {
    int s = p * 256 + tid;
    int row = s >> 5, c = s & 31;
    int gr = row0 + row; if (gr >= Mrows) gr = Mrows - 1;
    int cs = c ^ (row & 7);
    *(uint4*)&As[(size_t)s * 8] = *(const uint4*)&A[(size_t)gr * 256 + cs * 8];
  }
  __syncthreads();

  f32x4 acc[4][8];
  #pragma unroll
  for (int m = 0; m < 4; ++m)
    #pragma unroll
    for (int n = 0; n < 8; ++n) acc[m][n] = (f32x4){0.f, 0.f, 0.f, 0.f};

  const u16* bp[8];
  #pragma unroll
  for (int n = 0; n < 8; ++n) {
    int c = wc * 128 + n * 16 + fr;
    bp[n] = Bhi + (size_t)c * 256 + fg * 8;    // Blo at fixed +65536 offset
  }
  const size_t LO = 256 * 256;                 // Blo - Bhi element offset

  #pragma unroll
  for (int ks = 0; ks < 8; ++ks) {             // K = 8 x 32
    short8 a[4];
    #pragma unroll
    for (int m = 0; m < 4; ++m) {
      int r = wr * 64 + m * 16 + fr;
      int sl = (ks * 4 + fg) ^ (r & 7);
      a[m] = *(const short8*)&As[(size_t)(r * 32 + sl) * 8];
    }
    short8 bh[8];
    #pragma unroll
    for (int n = 0; n < 8; ++n) bh[n] = *(const short8*)(bp[n] + ks * 32);
    #pragma unroll
    for (int m = 0; m < 4; ++m)
      #pragma unroll
      for (int n = 0; n < 8; ++n)
        acc[m][n] = __builtin_amdgcn_mfma_f32_16x16x32_bf16(a[m], bh[n], acc[m][n], 0, 0, 0);
    short8 bl[8];
    #pragma unroll
    for (int n = 0; n < 8; ++n) bl[n] = *(const short8*)(bp[n] + LO + ks * 32);
    #pragma unroll
    for (int m = 0; m < 4; ++m)
      #pragma unroll
      for (int n = 0; n < 8; ++n)
        acc[m][n] = __builtin_amdgcn_mfma_f32_16x16x32_bf16(a[m], bl[n], acc[m][n], 0, 0, 0);
  }

  // C write (bf16): col=lane&15 within frag, row=(lane>>4)*4+j
  #pragma unroll
  for (int m = 0; m < 4; ++m) {
    #pragma unroll
    for (int n = 0; n < 8; ++n) {
      int col = wc * 128 + n * 16 + fr;
      #pragma unroll
      for (int j = 0; j < 4; ++j) {
        int row = row0 + wr * 64 + m * 16 + fg * 4 + j;
        if (row < Mrows) C16[(size_t)row * 256 + col] = f2bf_rn(acc[m][n][j]);
      }
    }
  }

  // fused logits: this wave's 128 cols = heads {wc*2, wc*2+1}
  float asv[8], adv[8];
  #pragma unroll
  for (int n = 0; n < 8; ++n) {
    int ii = (wc * 2 + (n >> 2)) * 64 + (n & 3) * 16 + fr;
    asv[n] = as_[ii];
    adv[n] = ad_[ii];
  }
  #pragma unroll
  for (int m = 0; m < 4; ++m) {
    #pragma unroll
    for (int j = 0; j < 4; ++j) {
      float ps0 = 0.f, pd0 = 0.f, ps1 = 0.f, pd1 = 0.f;
      #pragma unroll
      for (int n = 0; n < 4; ++n) {
        ps0 += acc[m][n][j] * asv[n];
        pd0 += acc[m][n][j] * adv[n];
        ps1 += acc[m][n + 4][j] * asv[n + 4];
        pd1 += acc[m][n + 4][j] * adv[n + 4];
      }
      #pragma unroll
      for (int off = 1; off < 16; off <<= 1) {
        ps0 += __shfl_xor(ps0, off, 64);
        pd0 += __shfl_xor(pd0, off, 64);
        ps1 += __shfl_xor(ps1, off, 64);
        pd1 += __shfl_xor(pd1, off, 64);
      }
      int grow = row0 + wr * 64 + m * 16 + fg * 4 + j;
      if (fr == 0 && grow < Mrows) {
        als[grow * 4 + wc * 2]     = ps0;
        als[grow * 4 + wc * 2 + 1] = ps1;
        ald[grow * 4 + wc * 2]     = pd0;
        ald[grow * 4 + wc * 2 + 1] = pd1;
      }
    }
  }
}

// ---------------- edge softmax: single pass, max-free ----------------
// logits are O(1)-bounded (|e| << 88), so exp() needs no max shift; the
// normalization alpha = p/S is mathematically identical to the reference.

__global__ void edge_softmax_kernel(const float* __restrict__ als, const float* __restrict__ ald,
                                    const int* __restrict__ rowptr, const int* __restrict__ col,
                                    float* __restrict__ w, float* __restrict__ invS, int Nn) {
  int node = blockIdx.x * 256 + threadIdx.x;
  if (node >= Nn) return;
  int rs = rowptr[node], re = rowptr[node + 1];
  float4 ad = *(const float4*)&ald[node * 4];
  float S0 = 0.f, S1 = 0.f, S2 = 0.f, S3 = 0.f;
  for (int i = rs; i < re; ++i) {
    int s = col[i];
    float4 a = *(const float4*)&als[(size_t)s * 4];
    float e0 = a.x + ad.x; e0 = e0 > 0.f ? e0 : NEG_SLOPE * e0;
    float e1 = a.y + ad.y; e1 = e1 > 0.f ? e1 : NEG_SLOPE * e1;
    float e2 = a.z + ad.z; e2 = e2 > 0.f ? e2 : NEG_SLOPE * e2;
    float e3 = a.w + ad.w; e3 = e3 > 0.f ? e3 : NEG_SLOPE * e3;
    float p0 = __expf(e0), p1 = __expf(e1), p2 = __expf(e2), p3 = __expf(e3);
    *(float4*)&w[(size_t)i * 4] = make_float4(p0, p1, p2, p3);
    S0 += p0; S1 += p1; S2 += p2; S3 += p3;
  }
  *(float4*)&invS[node * 4] = make_float4(1.f / (S0 + 1e-16f), 1.f / (S1 + 1e-16f),
                                          1.f / (S2 + 1e-16f), 1.f / (S3 + 1e-16f));
}

// ---------------- GAT gather v3: weighted sum, channel-pair dwords ----------------
// wave per node (scalarized); lane owns channels {2l, 2l+1, 128+2l, 128+2l+1}.
// Per edge: uniform col + uniform float4 w + 2 per-lane dword loads + 4 FMA.
// Output: bf16 packed u32 stores (feeds next GEMM's bf16 A, or the pool).

__global__ __launch_bounds__(256) void gat_gather_kernel(const u16* __restrict__ h16,
    const float* __restrict__ w, const float* __restrict__ invS,
    const int* __restrict__ rowptr, const int* __restrict__ col,
    const float* __restrict__ bias, u16* __restrict__ out16, int Nn) {
  int node = __builtin_amdgcn_readfirstlane(blockIdx.x * 4 + (threadIdx.x >> 6));
  int lane = threadIdx.x & 63;
  if (node >= Nn) return;
  int rs = rowptr[node], re = rowptr[node + 1];
  int hsel = lane >> 5;                       // head parity selector
  float a0 = 0.f, a1 = 0.f, a2 = 0.f, a3 = 0.f;
  const u32* h32 = (const u32*)h16;
  for (int i = rs; i < re; ++i) {
    int s = col[i];
    float4 wv = *(const float4*)&w[(size_t)i * 4];
    float wA = hsel ? wv.y : wv.x;
    float wB = hsel ? wv.w : wv.z;
    const u32* hr = h32 + (size_t)s * 128;
    u32 pa = hr[lane];                        // ch 2l, 2l+1   (head l>>5)
    u32 pb = hr[64 + lane];                   // ch 128+2l, 128+2l+1 (head 2+(l>>5))
    a0 += wA * __uint_as_float(pa << 16);
    a1 += wA * __uint_as_float(pa & 0xffff0000u);
    a2 += wB * __uint_as_float(pb << 16);
    a3 += wB * __uint_as_float(pb & 0xffff0000u);
  }
  float4 iS = *(const float4*)&invS[node * 4];
  float isA = hsel ? iS.y : iS.x;
  float isB = hsel ? iS.w : iS.z;
  float2 bA = *(const float2*)&bias[2 * lane];
  float2 bB = *(const float2*)&bias[128 + 2 * lane];
  float o0 = a0 * isA + bA.x;
  float o1 = a1 * isA + bA.y;
  float o2 = a2 * isB + bB.x;
  float o3 = a3 * isB + bB.y;
  o0 = o0 > 0.f ? o0 : (__expf(o0) - 1.0f);   // ELU (alpha=1)
  o1 = o1 > 0.f ? o1 : (__expf(o1) - 1.0f);
  o2 = o2 > 0.f ? o2 : (__expf(o2) - 1.0f);
  o3 = o3 > 0.f ? o3 : (__expf(o3) - 1.0f);
  u32* o32 = (u32*)out16;
  o32[(size_t)node * 128 + lane]      = (u32)f2bf_rn(o0) | ((u32)f2bf_rn(o1) << 16);
  o32[(size_t)node * 128 + 64 + lane] = (u32)f2bf_rn(o2) | ((u32)f2bf_rn(o3) << 16);
}

// ---------------- pooling + MLP ----------------

__global__ void bounds_kernel(const int* __restrict__ batch, int Nn, int* __restrict__ bounds) {
  int g = threadIdx.x;
  if (g > GG) return;
  int lo = 0, hi = Nn;
  while (lo < hi) { int mid = (lo + hi) >> 1; if (batch[mid] < g) lo = mid + 1; else hi = mid; }
  bounds[g] = lo;   // lower_bound of g; bounds[64] = N
}

__global__ void pool_kernel(const u16* __restrict__ X, const int* __restrict__ bounds,
                            float* __restrict__ pooled) {
  int g = blockIdx.x, split = blockIdx.y, t = threadIdx.x;
  int s = bounds[g], e = bounds[g + 1];
  int cnt = e - s;
  if (cnt <= 0) return;
  int chunk = (cnt + gridDim.y - 1) / gridDim.y;
  int s2 = s + split * chunk, e2 = min(e, s2 + chunk);
  if (s2 >= e2) return;
  float sum = 0.f;
  for (int n = s2; n < e2; ++n) sum += bf2f(X[(size_t)n * HC + t]);
  atomicAdd(&pooled[g * HC + t], sum);
}

__global__ __launch_bounds__(512) void mlp_kernel(const float* __restrict__ pooled,
    const int* __restrict__ bounds, const float* __restrict__ Wp1, const float* __restrict__ bp1,
    const float* __restrict__ Wp2, const float* __restrict__ bp2, float* __restrict__ out) {
  __shared__ float p[256];
  __shared__ float z1[512];
  int g = blockIdx.x, t = threadIdx.x;
  if (t < 256) {
    int cnt = bounds[g + 1] - bounds[g];
    float inv = 1.0f / (float)(cnt > 1 ? cnt : 1);
    p[t] = pooled[g * 256 + t] * inv;
  }
  __syncthreads();
  float a1 = bp1[t];
  for (int k = 0; k < 256; ++k) a1 += p[k] * Wp1[k * 512 + t];
  z1[t] = fmaxf(a1, 0.f);
  __syncthreads();
  if (t < 256) {
    float a2 = bp2[t];
    for (int k = 0; k < 512; ++k) a2 += z1[k] * Wp2[k * 256 + t];
    out[g * 256 + t] = a2;
  }
}

// ---------------- launch ----------------

static inline size_t align_up(size_t x, size_t a) { return (x + a - 1) & ~(a - 1); }

extern "C" void kernel_launch(void* const* d_in, const int* in_sizes, int n_in,
                              void* d_out, int out_size, void* d_ws, size_t ws_size,
                              hipStream_t stream) {
  const float* x    = (const float*)d_in[0];
  const int*   ei   = (const int*)d_in[1];
  const int*   batch= (const int*)d_in[2];
  const float* W1   = (const float*)d_in[3];
  const float* a1s  = (const float*)d_in[4];
  const float* a1d  = (const float*)d_in[5];
  const float* b1   = (const float*)d_in[6];
  const float* W2   = (const float*)d_in[7];
  const float* a2s  = (const float*)d_in[8];
  const float* a2d  = (const float*)d_in[9];
  const float* b2   = (const float*)d_in[10];
  const float* W3   = (const float*)d_in[11];
  const float* a3s  = (const float*)d_in[12];
  const float* a3d  = (const float*)d_in[13];
  const float* b3   = (const float*)d_in[14];
  const float* Wp1  = (const float*)d_in[15];
  const float* bp1  = (const float*)d_in[16];
  const float* Wp2  = (const float*)d_in[17];
  const float* bp2  = (const float*)d_in[18];

  const int N = in_sizes[0] / 2;       // 100000
  const int E = in_sizes[1] / 2;       // 400000
  const int Et = E + N;                // with self loops

  char* base = (char*)d_ws;
  size_t off = 0;
  auto alloc = [&](size_t bytes) { size_t o = off; off = align_up(off + bytes, 256); return o; };
  u16*   h16    = (u16*)  (base + alloc((size_t)N * HC * 2));   // message-path h (bf16)
  u16*   xhi    = (u16*)  (base + alloc((size_t)N * HC * 2));   // gather out (bf16)
  float* als    = (float*)(base + alloc((size_t)N * 4 * 4));
  float* ald    = (float*)(base + alloc((size_t)N * 4 * 4));
  float* invS   = (float*)(base + alloc((size_t)N * 4 * 4));
  int*   rowptr = (int*)  (base + alloc((size_t)(N + 1) * 4));
  int*   col    = (int*)  (base + alloc((size_t)Et * 4));
  float* w      = (float*)(base + alloc((size_t)Et * 4 * 4));   // per-edge softmax numerators
  int*   deg    = (int*)  (base + alloc((size_t)N * 4));
  int*   cursor = (int*)  (base + alloc((size_t)N * 4));
  int*   bsum   = (int*)  (base + alloc(512 * 4));
  int*   bounds = (int*)  (base + alloc((GG + 1) * 4));
  float* pooled = (float*)(base + alloc((size_t)GG * HC * 4));
  (void)ws_size; (void)n_in; (void)out_size;

  // W2t/W3t hi/lo parked in deg/cursor space (dead after CSR build; 400 KB >= 256 KB)
  // NOTE: hi and lo planes must be contiguous (gemm uses fixed +65536 offset).
  u16* W2thi = (u16*)deg;    u16* W2tlo = W2thi + 256 * 256;
  u16* W3thi = (u16*)cursor; u16* W3tlo = W3thi + 256 * 256;

  hipMemsetAsync(deg, 0, (size_t)N * 4, stream);
  hipMemsetAsync(cursor, 0, (size_t)N * 4, stream);
  hipMemsetAsync(pooled, 0, (size_t)GG * HC * 4, stream);

  // CSR by destination (same edge set for all layers)
  int ebk = (Et + 255) / 256;
  count_deg_kernel<<<ebk, 256, 0, stream>>>(ei, E, N, deg);
  int NT = (N + 255) / 256;
  scan_partial_kernel<<<NT, 256, 0, stream>>>(deg, N, rowptr, bsum);
  scan_bsum_kernel<<<1, 512, 0, stream>>>(bsum, NT);
  scan_add_kernel<<<NT, 256, 0, stream>>>(rowptr, bsum, N, Et);
  fill_csr_kernel<<<ebk, 256, 0, stream>>>(ei, E, N, rowptr, cursor, col);

  // weight conversion (deg/cursor now dead)
  convert_w_kernel<<<256, 256, 0, stream>>>(W2, W2thi, W2tlo);
  convert_w_kernel<<<256, 256, 0, stream>>>(W3, W3thi, W3tlo);

  int gemm_grid = (N + GBM - 1) / GBM;
  int nodeblk = (N + 3) / 4;

  // layer 1 (in=2, logits fused)
  gemm_k2_logits_kernel<<<nodeblk, 256, 0, stream>>>(x, W1, a1s, a1d, h16, als, ald, N);
  edge_softmax_kernel<<<NT, 256, 0, stream>>>(als, ald, rowptr, col, w, invS, N);
  gat_gather_kernel<<<nodeblk, 256, 0, stream>>>(h16, w, invS, rowptr, col, b1, xhi, N);
  // layer 2
  gemm_mfma_kernel<<<gemm_grid, 256, 0, stream>>>(xhi, W2thi, W2tlo, a2s, a2d,
                                                  h16, als, ald, N);
  edge_softmax_kernel<<<NT, 256, 0, stream>>>(als, ald, rowptr, col, w, invS, N);
  gat_gather_kernel<<<nodeblk, 256, 0, stream>>>(h16, w, invS, rowptr, col, b2, xhi, N);
  // layer 3
  gemm_mfma_kernel<<<gemm_grid, 256, 0, stream>>>(xhi, W3thi, W3tlo, a3s, a3d,
                                                  h16, als, ald, N);
  edge_softmax_kernel<<<NT, 256, 0, stream>>>(als, ald, rowptr, col, w, invS, N);
  gat_gather_kernel<<<nodeblk, 256, 0, stream>>>(h16, w, invS, rowptr, col, b3, xhi, N);

  // pool + MLP
  bounds_kernel<<<1, 128, 0, stream>>>(batch, N, bounds);
  pool_kernel<<<dim3(GG, 8), 256, 0, stream>>>(xhi, bounds, pooled);
  mlp_kernel<<<GG, 512, 0, stream>>>(pooled, bounds, Wp1, bp1, Wp2, bp2, (float*)d_out);
}

// Round 8
// 489.487 us; speedup vs baseline: 1.1999x; 1.1433x over previous
//
#include <hip/hip_runtime.h>
#include <math.h>

#define HC 256      // H*C
#define NHEAD 4
#define NEG_SLOPE 0.2f
#define GG 64       // graphs

typedef unsigned short u16;
typedef unsigned int u32;
typedef __attribute__((ext_vector_type(8))) short short8;
typedef __attribute__((ext_vector_type(4))) float f32x4;

static __device__ inline u16 f2bf_rn(float f) {
  u32 x = __float_as_uint(f);
  u32 r = (x + 0x7fffu + ((x >> 16) & 1u)) >> 16;
  return (u16)r;
}
static __device__ inline float bf2f(u16 u) { return __uint_as_float(((u32)u) << 16); }
static __device__ inline int swz(int b) { return b ^ (((b >> 8) & 7) << 4); }

// ---------------- CSR build ----------------

__global__ void count_deg_kernel(const int* __restrict__ ei, int E, int Nn, int* __restrict__ deg) {
  int idx = blockIdx.x * 256 + threadIdx.x;
  int Et = E + Nn;
  if (idx >= Et) return;
  int d = (idx < E) ? ei[E + idx] : (idx - E);   // row1 of edge_index = dst; self loops appended
  atomicAdd(&deg[d], 1);
}

__global__ void scan_partial_kernel(const int* __restrict__ deg, int Nn,
                                    int* __restrict__ rowptr, int* __restrict__ bsum) {
  __shared__ int s[256];
  int t = threadIdx.x, i = blockIdx.x * 256 + t;
  int v = (i < Nn) ? deg[i] : 0;
  s[t] = v; __syncthreads();
  for (int off = 1; off < 256; off <<= 1) {
    int x = (t >= off) ? s[t - off] : 0; __syncthreads();
    s[t] += x; __syncthreads();
  }
  if (i < Nn) rowptr[i] = s[t] - v;          // exclusive within block
  if (t == 255) bsum[blockIdx.x] = s[t];     // block total
}

__global__ void scan_bsum_kernel(int* __restrict__ bsum, int nb) {
  __shared__ int s[512];
  int t = threadIdx.x;
  int v = (t < nb) ? bsum[t] : 0;
  s[t] = v; __syncthreads();
  for (int off = 1; off < 512; off <<= 1) {
    int x = (t >= off) ? s[t - off] : 0; __syncthreads();
    s[t] += x; __syncthreads();
  }
  if (t < nb) bsum[t] = s[t] - v;            // exclusive block offsets
}

__global__ void scan_add_kernel(int* __restrict__ rowptr, const int* __restrict__ bsum,
                                int Nn, int Etot) {
  int i = blockIdx.x * 256 + threadIdx.x;
  if (i < Nn) rowptr[i] += bsum[blockIdx.x];
  if (i == 0) rowptr[Nn] = Etot;
}

__global__ void fill_csr_kernel(const int* __restrict__ ei, int E, int Nn,
                                const int* __restrict__ rowptr, int* __restrict__ cursor,
                                int* __restrict__ col) {
  int idx = blockIdx.x * 256 + threadIdx.x;
  int Et = E + Nn;
  if (idx >= Et) return;
  int s, d;
  if (idx < E) { s = ei[idx]; d = ei[E + idx]; } else { s = d = idx - E; }
  int pos = atomicAdd(&cursor[d], 1);
  col[rowptr[d] + pos] = s;
}

// ---------------- W transpose + bf16: Wt[n][k] ----------------

__global__ void convert_w_kernel(const float* __restrict__ W, u16* __restrict__ hi) {
  int idx = blockIdx.x * 256 + threadIdx.x;    // 65536 threads
  if (idx >= 256 * 256) return;
  int k = idx >> 8, n = idx & 255;             // coalesced read of W[k][n]
  hi[n * 256 + k] = f2bf_rn(W[idx]);
}

// ---------------- layer 1: K=2 GEMM fused with attention logits ----------------
// wave per node; h written as bf16 (message path); logits from fp32 values.

__global__ __launch_bounds__(256) void gemm_k2_logits_kernel(
    const float* __restrict__ x, const float* __restrict__ W,
    const float* __restrict__ as_, const float* __restrict__ ad_,
    u16* __restrict__ h16, float* __restrict__ als, float* __restrict__ ald, int Nn) {
  int node = blockIdx.x * 4 + (threadIdx.x >> 6);
  int lane = threadIdx.x & 63;
  if (node >= Nn) return;
  float x0 = x[node * 2], x1 = x[node * 2 + 1];
  float ps[4], pd[4];
  #pragma unroll
  for (int q = 0; q < 4; ++q) {
    int c = q * 64 + lane;
    float o = x0 * W[c] + x1 * W[256 + c];
    h16[(size_t)node * HC + c] = f2bf_rn(o);
    ps[q] = o * as_[c];
    pd[q] = o * ad_[c];
  }
  #pragma unroll
  for (int off = 32; off >= 1; off >>= 1) {
    #pragma unroll
    for (int q = 0; q < 4; ++q) {
      ps[q] += __shfl_xor(ps[q], off, 64);
      pd[q] += __shfl_xor(pd[q], off, 64);
    }
  }
  if (lane == 0) {
    *(float4*)&als[node * 4] = make_float4(ps[0], ps[1], ps[2], ps[3]);
    *(float4*)&ald[node * 4] = make_float4(pd[0], pd[1], pd[2], pd[3]);
  }
}

// ---------------- pipelined LDS MFMA GEMM (2-phase, T14 issue-early) ----------------
// A bf16 [M][256]; B = Wt bf16 [256][256] (single plane).  BM=128, BN=128, BK=32.
// Double-buffered 32KB LDS; per K-step: issue next tile's 4 global loads first,
// 8 swizzled ds_read_b128 (XOR b^=((b>>8)&7)<<4 -> ~2-way aliasing, free),
// 16 MFMA, ds_write next buffer, one barrier. Latency hidden by pipeline + TLP.
// C written bf16; fused logits from fp32 acc (wave's 64 cols = head bc*2+wc).

#define GBM 128
#define GBN 128

__global__ __launch_bounds__(256) void gemm_mfma_kernel(
    const u16* __restrict__ A, const u16* __restrict__ Bt,
    const float* __restrict__ as_, const float* __restrict__ ad_,
    u16* __restrict__ C16, float* __restrict__ als, float* __restrict__ ald, int Mrows) {
  __shared__ __align__(16) u16 sA[2][4096];   // 2 x 8KB
  __shared__ __align__(16) u16 sB[2][4096];   // 2 x 8KB
  char* sAc = (char*)&sA[0][0];
  char* sBc = (char*)&sB[0][0];
  int bc = blockIdx.x, br = blockIdx.y;
  int tid = threadIdx.x;
  int wid = tid >> 6, lane = tid & 63;
  int wr = wid >> 1, wc = wid & 1;             // 2x2 waves; each 64x64 output
  int row0 = br * GBM, col0 = bc * GBN;
  int fr = lane & 15, fg = lane >> 4;

  // staging geometry: wave stages rows/cols wid*32 + j*16 + (lane>>2), kchunk lane&3
  const u16* agp[2];
  const u16* bgp[2];
  int wof[2];
  #pragma unroll
  for (int j = 0; j < 2; ++j) {
    int rr = wid * 32 + j * 16 + (lane >> 2);
    int kc = lane & 3;
    int gr = row0 + rr; if (gr >= Mrows) gr = Mrows - 1;
    agp[j] = A + (size_t)gr * 256 + kc * 8;
    bgp[j] = Bt + (size_t)(col0 + rr) * 256 + kc * 8;
    wof[j] = swz(rr * 64 + kc * 16);
  }
  int rofA[4], rofB[4];
  #pragma unroll
  for (int m = 0; m < 4; ++m) rofA[m] = swz((wr * 64 + m * 16 + fr) * 64 + fg * 16);
  #pragma unroll
  for (int n = 0; n < 4; ++n) rofB[n] = swz((wc * 64 + n * 16 + fr) * 64 + fg * 16);

  f32x4 acc[4][4];
  #pragma unroll
  for (int m = 0; m < 4; ++m)
    #pragma unroll
    for (int n = 0; n < 4; ++n) acc[m][n] = (f32x4){0.f, 0.f, 0.f, 0.f};

  // prologue: stage tile 0
  uint4 va[2], vb[2];
  #pragma unroll
  for (int j = 0; j < 2; ++j) { va[j] = *(const uint4*)agp[j]; vb[j] = *(const uint4*)bgp[j]; }
  #pragma unroll
  for (int j = 0; j < 2; ++j) {
    *(uint4*)(sAc + wof[j]) = va[j];
    *(uint4*)(sBc + wof[j]) = vb[j];
  }
  __syncthreads();

  #pragma unroll
  for (int kt = 0; kt < 8; ++kt) {             // K = 8 x 32
    int buf = kt & 1;
    if (kt < 7) {                              // T14: issue next-tile loads early
      #pragma unroll
      for (int j = 0; j < 2; ++j) {
        va[j] = *(const uint4*)(agp[j] + (kt + 1) * 32);
        vb[j] = *(const uint4*)(bgp[j] + (kt + 1) * 32);
      }
    }
    short8 af[4], bf[4];
    #pragma unroll
    for (int m = 0; m < 4; ++m) af[m] = *(const short8*)(sAc + buf * 8192 + rofA[m]);
    #pragma unroll
    for (int n = 0; n < 4; ++n) bf[n] = *(const short8*)(sBc + buf * 8192 + rofB[n]);
    #pragma unroll
    for (int m = 0; m < 4; ++m)
      #pragma unroll
      for (int n = 0; n < 4; ++n)
        acc[m][n] = __builtin_amdgcn_mfma_f32_16x16x32_bf16(af[m], bf[n], acc[m][n], 0, 0, 0);
    if (kt < 7) {                              // write next buffer, one barrier
      int nb = buf ^ 1;
      #pragma unroll
      for (int j = 0; j < 2; ++j) {
        *(uint4*)(sAc + nb * 8192 + wof[j]) = va[j];
        *(uint4*)(sBc + nb * 8192 + wof[j]) = vb[j];
      }
      __syncthreads();
    }
  }

  // C write (bf16): col=lane&15 within frag, row=(lane>>4)*4+j
  #pragma unroll
  for (int m = 0; m < 4; ++m) {
    #pragma unroll
    for (int n = 0; n < 4; ++n) {
      int col = col0 + wc * 64 + n * 16 + fr;
      #pragma unroll
      for (int j = 0; j < 4; ++j) {
        int row = row0 + wr * 64 + m * 16 + fg * 4 + j;
        if (row < Mrows) C16[(size_t)row * 256 + col] = f2bf_rn(acc[m][n][j]);
      }
    }
  }

  // fused logits: this wave's 64 cols = one head
  int head = bc * 2 + wc;
  float asv[4], adv[4];
  #pragma unroll
  for (int n = 0; n < 4; ++n) {
    asv[n] = as_[head * 64 + n * 16 + fr];
    adv[n] = ad_[head * 64 + n * 16 + fr];
  }
  #pragma unroll
  for (int m = 0; m < 4; ++m) {
    #pragma unroll
    for (int j = 0; j < 4; ++j) {
      float ps = 0.f, pd = 0.f;
      #pragma unroll
      for (int n = 0; n < 4; ++n) {
        ps += acc[m][n][j] * asv[n];
        pd += acc[m][n][j] * adv[n];
      }
      #pragma unroll
      for (int off = 1; off < 16; off <<= 1) {
        ps += __shfl_xor(ps, off, 64);
        pd += __shfl_xor(pd, off, 64);
      }
      int grow = row0 + wr * 64 + m * 16 + fg * 4 + j;
      if (fr == 0 && grow < Mrows) {
        als[grow * 4 + head] = ps;
        ald[grow * 4 + head] = pd;
      }
    }
  }
}

// ---------------- edge softmax: single pass, max-free ----------------

__global__ void edge_softmax_kernel(const float* __restrict__ als, const float* __restrict__ ald,
                                    const int* __restrict__ rowptr, const int* __restrict__ col,
                                    float* __restrict__ w, float* __restrict__ invS, int Nn) {
  int node = blockIdx.x * 256 + threadIdx.x;
  if (node >= Nn) return;
  int rs = rowptr[node], re = rowptr[node + 1];
  float4 ad = *(const float4*)&ald[node * 4];
  float S0 = 0.f, S1 = 0.f, S2 = 0.f, S3 = 0.f;
  for (int i = rs; i < re; ++i) {
    int s = col[i];
    float4 a = *(const float4*)&als[(size_t)s * 4];
    float e0 = a.x + ad.x; e0 = e0 > 0.f ? e0 : NEG_SLOPE * e0;
    float e1 = a.y + ad.y; e1 = e1 > 0.f ? e1 : NEG_SLOPE * e1;
    float e2 = a.z + ad.z; e2 = e2 > 0.f ? e2 : NEG_SLOPE * e2;
    float e3 = a.w + ad.w; e3 = e3 > 0.f ? e3 : NEG_SLOPE * e3;
    float p0 = __expf(e0), p1 = __expf(e1), p2 = __expf(e2), p3 = __expf(e3);
    *(float4*)&w[(size_t)i * 4] = make_float4(p0, p1, p2, p3);
    S0 += p0; S1 += p1; S2 += p2; S3 += p3;
  }
  *(float4*)&invS[node * 4] = make_float4(1.f / (S0 + 1e-16f), 1.f / (S1 + 1e-16f),
                                          1.f / (S2 + 1e-16f), 1.f / (S3 + 1e-16f));
}

// ---------------- GAT gather v3: weighted sum, channel-pair dwords ----------------

__global__ __launch_bounds__(256) void gat_gather_kernel(const u16* __restrict__ h16,
    const float* __restrict__ w, const float* __restrict__ invS,
    const int* __restrict__ rowptr, const int* __restrict__ col,
    const float* __restrict__ bias, u16* __restrict__ out16, int Nn) {
  int node = __builtin_amdgcn_readfirstlane(blockIdx.x * 4 + (threadIdx.x >> 6));
  int lane = threadIdx.x & 63;
  if (node >= Nn) return;
  int rs = rowptr[node], re = rowptr[node + 1];
  int hsel = lane >> 5;                       // head parity selector
  float a0 = 0.f, a1 = 0.f, a2 = 0.f, a3 = 0.f;
  const u32* h32 = (const u32*)h16;
  for (int i = rs; i < re; ++i) {
    int s = col[i];
    float4 wv = *(const float4*)&w[(size_t)i * 4];
    float wA = hsel ? wv.y : wv.x;
    float wB = hsel ? wv.w : wv.z;
    const u32* hr = h32 + (size_t)s * 128;
    u32 pa = hr[lane];                        // ch 2l, 2l+1   (head l>>5)
    u32 pb = hr[64 + lane];                   // ch 128+2l, 128+2l+1 (head 2+(l>>5))
    a0 += wA * __uint_as_float(pa << 16);
    a1 += wA * __uint_as_float(pa & 0xffff0000u);
    a2 += wB * __uint_as_float(pb << 16);
    a3 += wB * __uint_as_float(pb & 0xffff0000u);
  }
  float4 iS = *(const float4*)&invS[node * 4];
  float isA = hsel ? iS.y : iS.x;
  float isB = hsel ? iS.w : iS.z;
  float2 bA = *(const float2*)&bias[2 * lane];
  float2 bB = *(const float2*)&bias[128 + 2 * lane];
  float o0 = a0 * isA + bA.x;
  float o1 = a1 * isA + bA.y;
  float o2 = a2 * isB + bB.x;
  float o3 = a3 * isB + bB.y;
  o0 = o0 > 0.f ? o0 : (__expf(o0) - 1.0f);   // ELU (alpha=1)
  o1 = o1 > 0.f ? o1 : (__expf(o1) - 1.0f);
  o2 = o2 > 0.f ? o2 : (__expf(o2) - 1.0f);
  o3 = o3 > 0.f ? o3 : (__expf(o3) - 1.0f);
  u32* o32 = (u32*)out16;
  o32[(size_t)node * 128 + lane]      = (u32)f2bf_rn(o0) | ((u32)f2bf_rn(o1) << 16);
  o32[(size_t)node * 128 + 64 + lane] = (u32)f2bf_rn(o2) | ((u32)f2bf_rn(o3) << 16);
}

// ---------------- pooling + MLP ----------------

__global__ void bounds_kernel(const int* __restrict__ batch, int Nn, int* __restrict__ bounds) {
  int g = threadIdx.x;
  if (g > GG) return;
  int lo = 0, hi = Nn;
  while (lo < hi) { int mid = (lo + hi) >> 1; if (batch[mid] < g) lo = mid + 1; else hi = mid; }
  bounds[g] = lo;   // lower_bound of g; bounds[64] = N
}

__global__ void pool_kernel(const u16* __restrict__ X, const int* __restrict__ bounds,
                            float* __restrict__ pooled) {
  int g = blockIdx.x, split = blockIdx.y, t = threadIdx.x;
  int s = bounds[g], e = bounds[g + 1];
  int cnt = e - s;
  if (cnt <= 0) return;
  int chunk = (cnt + gridDim.y - 1) / gridDim.y;
  int s2 = s + split * chunk, e2 = min(e, s2 + chunk);
  if (s2 >= e2) return;
  float sum = 0.f;
  for (int n = s2; n < e2; ++n) sum += bf2f(X[(size_t)n * HC + t]);
  atomicAdd(&pooled[g * HC + t], sum);
}

__global__ __launch_bounds__(512) void mlp_kernel(const float* __restrict__ pooled,
    const int* __restrict__ bounds, const float* __restrict__ Wp1, const float* __restrict__ bp1,
    const float* __restrict__ Wp2, const float* __restrict__ bp2, float* __restrict__ out) {
  __shared__ float p[256];
  __shared__ float z1[512];
  int g = blockIdx.x, t = threadIdx.x;
  if (t < 256) {
    int cnt = bounds[g + 1] - bounds[g];
    float inv = 1.0f / (float)(cnt > 1 ? cnt : 1);
    p[t] = pooled[g * 256 + t] * inv;
  }
  __syncthreads();
  float a1 = bp1[t];
  for (int k = 0; k < 256; ++k) a1 += p[k] * Wp1[k * 512 + t];
  z1[t] = fmaxf(a1, 0.f);
  __syncthreads();
  if (t < 256) {
    float a2 = bp2[t];
    for (int k = 0; k < 512; ++k) a2 += z1[k] * Wp2[k * 256 + t];
    out[g * 256 + t] = a2;
  }
}

// ---------------- launch ----------------

static inline size_t align_up(size_t x, size_t a) { return (x + a - 1) & ~(a - 1); }

extern "C" void kernel_launch(void* const* d_in, const int* in_sizes, int n_in,
                              void* d_out, int out_size, void* d_ws, size_t ws_size,
                              hipStream_t stream) {
  const float* x    = (const float*)d_in[0];
  const int*   ei   = (const int*)d_in[1];
  const int*   batch= (const int*)d_in[2];
  const float* W1   = (const float*)d_in[3];
  const float* a1s  = (const float*)d_in[4];
  const float* a1d  = (const float*)d_in[5];
  const float* b1   = (const float*)d_in[6];
  const float* W2   = (const float*)d_in[7];
  const float* a2s  = (const float*)d_in[8];
  const float* a2d  = (const float*)d_in[9];
  const float* b2   = (const float*)d_in[10];
  const float* W3   = (const float*)d_in[11];
  const float* a3s  = (const float*)d_in[12];
  const float* a3d  = (const float*)d_in[13];
  const float* b3   = (const float*)d_in[14];
  const float* Wp1  = (const float*)d_in[15];
  const float* bp1  = (const float*)d_in[16];
  const float* Wp2  = (const float*)d_in[17];
  const float* bp2  = (const float*)d_in[18];

  const int N = in_sizes[0] / 2;       // 100000
  const int E = in_sizes[1] / 2;       // 400000
  const int Et = E + N;                // with self loops

  char* base = (char*)d_ws;
  size_t off = 0;
  auto alloc = [&](size_t bytes) { size_t o = off; off = align_up(off + bytes, 256); return o; };
  u16*   h16    = (u16*)  (base + alloc((size_t)N * HC * 2));   // message-path h (bf16)
  u16*   xhi    = (u16*)  (base + alloc((size_t)N * HC * 2));   // gather out (bf16)
  float* als    = (float*)(base + alloc((size_t)N * 4 * 4));
  float* ald    = (float*)(base + alloc((size_t)N * 4 * 4));
  float* invS   = (float*)(base + alloc((size_t)N * 4 * 4));
  int*   rowptr = (int*)  (base + alloc((size_t)(N + 1) * 4));
  int*   col    = (int*)  (base + alloc((size_t)Et * 4));
  float* w      = (float*)(base + alloc((size_t)Et * 4 * 4));   // per-edge softmax numerators
  int*   deg    = (int*)  (base + alloc((size_t)N * 4));
  int*   cursor = (int*)  (base + alloc((size_t)N * 4));
  int*   bsum   = (int*)  (base + alloc(512 * 4));
  int*   bounds = (int*)  (base + alloc((GG + 1) * 4));
  float* pooled = (float*)(base + alloc((size_t)GG * HC * 4));
  (void)ws_size; (void)n_in; (void)out_size;

  // W2t/W3t (bf16, 128KB each) parked in deg/cursor space (dead after CSR build)
  u16* W2t = (u16*)deg;
  u16* W3t = (u16*)cursor;

  hipMemsetAsync(deg, 0, (size_t)N * 4, stream);
  hipMemsetAsync(cursor, 0, (size_t)N * 4, stream);
  hipMemsetAsync(pooled, 0, (size_t)GG * HC * 4, stream);

  // CSR by destination (same edge set for all layers)
  int ebk = (Et + 255) / 256;
  count_deg_kernel<<<ebk, 256, 0, stream>>>(ei, E, N, deg);
  int NT = (N + 255) / 256;
  scan_partial_kernel<<<NT, 256, 0, stream>>>(deg, N, rowptr, bsum);
  scan_bsum_kernel<<<1, 512, 0, stream>>>(bsum, NT);
  scan_add_kernel<<<NT, 256, 0, stream>>>(rowptr, bsum, N, Et);
  fill_csr_kernel<<<ebk, 256, 0, stream>>>(ei, E, N, rowptr, cursor, col);

  // weight conversion (deg/cursor now dead)
  convert_w_kernel<<<256, 256, 0, stream>>>(W2, W2t);
  convert_w_kernel<<<256, 256, 0, stream>>>(W3, W3t);

  dim3 gemm_grid(HC / GBN, (N + GBM - 1) / GBM);
  int nodeblk = (N + 3) / 4;

  // layer 1 (in=2, logits fused)
  gemm_k2_logits_kernel<<<nodeblk, 256, 0, stream>>>(x, W1, a1s, a1d, h16, als, ald, N);
  edge_softmax_kernel<<<NT, 256, 0, stream>>>(als, ald, rowptr, col, w, invS, N);
  gat_gather_kernel<<<nodeblk, 256, 0, stream>>>(h16, w, invS, rowptr, col, b1, xhi, N);
  // layer 2
  gemm_mfma_kernel<<<gemm_grid, 256, 0, stream>>>(xhi, W2t, a2s, a2d, h16, als, ald, N);
  edge_softmax_kernel<<<NT, 256, 0, stream>>>(als, ald, rowptr, col, w, invS, N);
  gat_gather_kernel<<<nodeblk, 256, 0, stream>>>(h16, w, invS, rowptr, col, b2, xhi, N);
  // layer 3
  gemm_mfma_kernel<<<gemm_grid, 256, 0, stream>>>(xhi, W3t, a3s, a3d, h16, als, ald, N);
  edge_softmax_kernel<<<NT, 256, 0, stream>>>(als, ald, rowptr, col, w, invS, N);
  gat_gather_kernel<<<nodeblk, 256, 0, stream>>>(h16, w, invS, rowptr, col, b3, xhi, N);

  // pool + MLP
  bounds_kernel<<<1, 128, 0, stream>>>(batch, N, bounds);
  pool_kernel<<<dim3(GG, 8), 256, 0, stream>>>(xhi, bounds, pooled);
  mlp_kernel<<<GG, 512, 0, stream>>>(pooled, bounds, Wp1, bp1, Wp2, bp2, (float*)d_out);
}

// Round 9
// 459.712 us; speedup vs baseline: 1.2777x; 1.0648x over previous
//
#include <hip/hip_runtime.h>
#include <math.h>

#define HC 256      // H*C
#define NHEAD 4
#define NEG_SLOPE 0.2f
#define GG 64       // graphs

typedef unsigned short u16;
typedef unsigned int u32;
typedef __attribute__((ext_vector_type(8))) short short8;
typedef __attribute__((ext_vector_type(4))) float f32x4;

static __device__ inline u16 f2bf_rn(float f) {
  u32 x = __float_as_uint(f);
  u32 r = (x + 0x7fffu + ((x >> 16) & 1u)) >> 16;
  return (u16)r;
}
static __device__ inline float bf2f(u16 u) { return __uint_as_float(((u32)u) << 16); }
static __device__ inline int swz(int b) { return b ^ (((b >> 8) & 7) << 4); }

// ---------------- CSR build ----------------

__global__ void count_deg_kernel(const int* __restrict__ ei, int E, int Nn, int* __restrict__ deg) {
  int idx = blockIdx.x * 256 + threadIdx.x;
  int Et = E + Nn;
  if (idx >= Et) return;
  int d = (idx < E) ? ei[E + idx] : (idx - E);   // row1 of edge_index = dst; self loops appended
  atomicAdd(&deg[d], 1);
}

__global__ void scan_partial_kernel(const int* __restrict__ deg, int Nn,
                                    int* __restrict__ rowptr, int* __restrict__ bsum) {
  __shared__ int s[256];
  int t = threadIdx.x, i = blockIdx.x * 256 + t;
  int v = (i < Nn) ? deg[i] : 0;
  s[t] = v; __syncthreads();
  for (int off = 1; off < 256; off <<= 1) {
    int x = (t >= off) ? s[t - off] : 0; __syncthreads();
    s[t] += x; __syncthreads();
  }
  if (i < Nn) rowptr[i] = s[t] - v;          // exclusive within block
  if (t == 255) bsum[blockIdx.x] = s[t];     // block total
}

__global__ void scan_bsum_kernel(int* __restrict__ bsum, int nb) {
  __shared__ int s[512];
  int t = threadIdx.x;
  int v = (t < nb) ? bsum[t] : 0;
  s[t] = v; __syncthreads();
  for (int off = 1; off < 512; off <<= 1) {
    int x = (t >= off) ? s[t - off] : 0; __syncthreads();
    s[t] += x; __syncthreads();
  }
  if (t < nb) bsum[t] = s[t] - v;            // exclusive block offsets
}

__global__ void scan_add_kernel(int* __restrict__ rowptr, const int* __restrict__ bsum,
                                int Nn, int Etot) {
  int i = blockIdx.x * 256 + threadIdx.x;
  if (i < Nn) rowptr[i] += bsum[blockIdx.x];
  if (i == 0) rowptr[Nn] = Etot;
}

__global__ void fill_csr_kernel(const int* __restrict__ ei, int E, int Nn,
                                const int* __restrict__ rowptr, int* __restrict__ cursor,
                                int* __restrict__ col) {
  int idx = blockIdx.x * 256 + threadIdx.x;
  int Et = E + Nn;
  if (idx >= Et) return;
  int s, d;
  if (idx < E) { s = ei[idx]; d = ei[E + idx]; } else { s = d = idx - E; }
  int pos = atomicAdd(&cursor[d], 1);
  col[rowptr[d] + pos] = s;
}

// ---------------- W transpose + bf16: Wt[n][k] ----------------

__global__ void convert_w_kernel(const float* __restrict__ W, u16* __restrict__ hi) {
  int idx = blockIdx.x * 256 + threadIdx.x;    // 65536 threads
  if (idx >= 256 * 256) return;
  int k = idx >> 8, n = idx & 255;             // coalesced read of W[k][n]
  hi[n * 256 + k] = f2bf_rn(W[idx]);
}

// ---------------- layer 1: K=2 GEMM fused with attention logits ----------------
// wave per node; h written as bf16 (message path); logits from fp32 values.

__global__ __launch_bounds__(256) void gemm_k2_logits_kernel(
    const float* __restrict__ x, const float* __restrict__ W,
    const float* __restrict__ as_, const float* __restrict__ ad_,
    u16* __restrict__ h16, float* __restrict__ als, float* __restrict__ ald, int Nn) {
  int node = blockIdx.x * 4 + (threadIdx.x >> 6);
  int lane = threadIdx.x & 63;
  if (node >= Nn) return;
  float x0 = x[node * 2], x1 = x[node * 2 + 1];
  float ps[4], pd[4];
  #pragma unroll
  for (int q = 0; q < 4; ++q) {
    int c = q * 64 + lane;
    float o = x0 * W[c] + x1 * W[256 + c];
    h16[(size_t)node * HC + c] = f2bf_rn(o);
    ps[q] = o * as_[c];
    pd[q] = o * ad_[c];
  }
  #pragma unroll
  for (int off = 32; off >= 1; off >>= 1) {
    #pragma unroll
    for (int q = 0; q < 4; ++q) {
      ps[q] += __shfl_xor(ps[q], off, 64);
      pd[q] += __shfl_xor(pd[q], off, 64);
    }
  }
  if (lane == 0) {
    *(float4*)&als[node * 4] = make_float4(ps[0], ps[1], ps[2], ps[3]);
    *(float4*)&ald[node * 4] = make_float4(pd[0], pd[1], pd[2], pd[3]);
  }
}

// ---------------- pipelined LDS MFMA GEMM (2-phase, T14 issue-early) ----------------

#define GBM 128
#define GBN 128

__global__ __launch_bounds__(256) void gemm_mfma_kernel(
    const u16* __restrict__ A, const u16* __restrict__ Bt,
    const float* __restrict__ as_, const float* __restrict__ ad_,
    u16* __restrict__ C16, float* __restrict__ als, float* __restrict__ ald, int Mrows) {
  __shared__ __align__(16) u16 sA[2][4096];   // 2 x 8KB
  __shared__ __align__(16) u16 sB[2][4096];   // 2 x 8KB
  char* sAc = (char*)&sA[0][0];
  char* sBc = (char*)&sB[0][0];
  int bc = blockIdx.x, br = blockIdx.y;
  int tid = threadIdx.x;
  int wid = tid >> 6, lane = tid & 63;
  int wr = wid >> 1, wc = wid & 1;             // 2x2 waves; each 64x64 output
  int row0 = br * GBM, col0 = bc * GBN;
  int fr = lane & 15, fg = lane >> 4;

  const u16* agp[2];
  const u16* bgp[2];
  int wof[2];
  #pragma unroll
  for (int j = 0; j < 2; ++j) {
    int rr = wid * 32 + j * 16 + (lane >> 2);
    int kc = lane & 3;
    int gr = row0 + rr; if (gr >= Mrows) gr = Mrows - 1;
    agp[j] = A + (size_t)gr * 256 + kc * 8;
    bgp[j] = Bt + (size_t)(col0 + rr) * 256 + kc * 8;
    wof[j] = swz(rr * 64 + kc * 16);
  }
  int rofA[4], rofB[4];
  #pragma unroll
  for (int m = 0; m < 4; ++m) rofA[m] = swz((wr * 64 + m * 16 + fr) * 64 + fg * 16);
  #pragma unroll
  for (int n = 0; n < 4; ++n) rofB[n] = swz((wc * 64 + n * 16 + fr) * 64 + fg * 16);

  f32x4 acc[4][4];
  #pragma unroll
  for (int m = 0; m < 4; ++m)
    #pragma unroll
    for (int n = 0; n < 4; ++n) acc[m][n] = (f32x4){0.f, 0.f, 0.f, 0.f};

  uint4 va[2], vb[2];
  #pragma unroll
  for (int j = 0; j < 2; ++j) { va[j] = *(const uint4*)agp[j]; vb[j] = *(const uint4*)bgp[j]; }
  #pragma unroll
  for (int j = 0; j < 2; ++j) {
    *(uint4*)(sAc + wof[j]) = va[j];
    *(uint4*)(sBc + wof[j]) = vb[j];
  }
  __syncthreads();

  #pragma unroll
  for (int kt = 0; kt < 8; ++kt) {             // K = 8 x 32
    int buf = kt & 1;
    if (kt < 7) {                              // T14: issue next-tile loads early
      #pragma unroll
      for (int j = 0; j < 2; ++j) {
        va[j] = *(const uint4*)(agp[j] + (kt + 1) * 32);
        vb[j] = *(const uint4*)(bgp[j] + (kt + 1) * 32);
      }
    }
    short8 af[4], bf[4];
    #pragma unroll
    for (int m = 0; m < 4; ++m) af[m] = *(const short8*)(sAc + buf * 8192 + rofA[m]);
    #pragma unroll
    for (int n = 0; n < 4; ++n) bf[n] = *(const short8*)(sBc + buf * 8192 + rofB[n]);
    #pragma unroll
    for (int m = 0; m < 4; ++m)
      #pragma unroll
      for (int n = 0; n < 4; ++n)
        acc[m][n] = __builtin_amdgcn_mfma_f32_16x16x32_bf16(af[m], bf[n], acc[m][n], 0, 0, 0);
    if (kt < 7) {                              // write next buffer, one barrier
      int nb = buf ^ 1;
      #pragma unroll
      for (int j = 0; j < 2; ++j) {
        *(uint4*)(sAc + nb * 8192 + wof[j]) = va[j];
        *(uint4*)(sBc + nb * 8192 + wof[j]) = vb[j];
      }
      __syncthreads();
    }
  }

  // C write (bf16): col=lane&15 within frag, row=(lane>>4)*4+j
  #pragma unroll
  for (int m = 0; m < 4; ++m) {
    #pragma unroll
    for (int n = 0; n < 4; ++n) {
      int col = col0 + wc * 64 + n * 16 + fr;
      #pragma unroll
      for (int j = 0; j < 4; ++j) {
        int row = row0 + wr * 64 + m * 16 + fg * 4 + j;
        if (row < Mrows) C16[(size_t)row * 256 + col] = f2bf_rn(acc[m][n][j]);
      }
    }
  }

  // fused logits: this wave's 64 cols = one head
  int head = bc * 2 + wc;
  float asv[4], adv[4];
  #pragma unroll
  for (int n = 0; n < 4; ++n) {
    asv[n] = as_[head * 64 + n * 16 + fr];
    adv[n] = ad_[head * 64 + n * 16 + fr];
  }
  #pragma unroll
  for (int m = 0; m < 4; ++m) {
    #pragma unroll
    for (int j = 0; j < 4; ++j) {
      float ps = 0.f, pd = 0.f;
      #pragma unroll
      for (int n = 0; n < 4; ++n) {
        ps += acc[m][n][j] * asv[n];
        pd += acc[m][n][j] * adv[n];
      }
      #pragma unroll
      for (int off = 1; off < 16; off <<= 1) {
        ps += __shfl_xor(ps, off, 64);
        pd += __shfl_xor(pd, off, 64);
      }
      int grow = row0 + wr * 64 + m * 16 + fg * 4 + j;
      if (fr == 0 && grow < Mrows) {
        als[grow * 4 + head] = ps;
        ald[grow * 4 + head] = pd;
      }
    }
  }
}

// ---------------- edge softmax: single pass, max-free ----------------

__global__ void edge_softmax_kernel(const float* __restrict__ als, const float* __restrict__ ald,
                                    const int* __restrict__ rowptr, const int* __restrict__ col,
                                    float* __restrict__ w, float* __restrict__ invS, int Nn) {
  int node = blockIdx.x * 256 + threadIdx.x;
  if (node >= Nn) return;
  int rs = rowptr[node], re = rowptr[node + 1];
  float4 ad = *(const float4*)&ald[node * 4];
  float S0 = 0.f, S1 = 0.f, S2 = 0.f, S3 = 0.f;
  for (int i = rs; i < re; ++i) {
    int s = col[i];
    float4 a = *(const float4*)&als[(size_t)s * 4];
    float e0 = a.x + ad.x; e0 = e0 > 0.f ? e0 : NEG_SLOPE * e0;
    float e1 = a.y + ad.y; e1 = e1 > 0.f ? e1 : NEG_SLOPE * e1;
    float e2 = a.z + ad.z; e2 = e2 > 0.f ? e2 : NEG_SLOPE * e2;
    float e3 = a.w + ad.w; e3 = e3 > 0.f ? e3 : NEG_SLOPE * e3;
    float p0 = __expf(e0), p1 = __expf(e1), p2 = __expf(e2), p3 = __expf(e3);
    *(float4*)&w[(size_t)i * 4] = make_float4(p0, p1, p2, p3);
    S0 += p0; S1 += p1; S2 += p2; S3 += p3;
  }
  *(float4*)&invS[node * 4] = make_float4(1.f / (S0 + 1e-16f), 1.f / (S1 + 1e-16f),
                                          1.f / (S2 + 1e-16f), 1.f / (S3 + 1e-16f));
}

// ---------------- GAT gather v3: weighted sum, channel-pair dwords ----------------

__global__ __launch_bounds__(256) void gat_gather_kernel(const u16* __restrict__ h16,
    const float* __restrict__ w, const float* __restrict__ invS,
    const int* __restrict__ rowptr, const int* __restrict__ col,
    const float* __restrict__ bias, u16* __restrict__ out16, int Nn) {
  int node = __builtin_amdgcn_readfirstlane(blockIdx.x * 4 + (threadIdx.x >> 6));
  int lane = threadIdx.x & 63;
  if (node >= Nn) return;
  int rs = rowptr[node], re = rowptr[node + 1];
  int hsel = lane >> 5;                       // head parity selector
  float a0 = 0.f, a1 = 0.f, a2 = 0.f, a3 = 0.f;
  const u32* h32 = (const u32*)h16;
  for (int i = rs; i < re; ++i) {
    int s = col[i];
    float4 wv = *(const float4*)&w[(size_t)i * 4];
    float wA = hsel ? wv.y : wv.x;
    float wB = hsel ? wv.w : wv.z;
    const u32* hr = h32 + (size_t)s * 128;
    u32 pa = hr[lane];                        // ch 2l, 2l+1   (head l>>5)
    u32 pb = hr[64 + lane];                   // ch 128+2l, 128+2l+1 (head 2+(l>>5))
    a0 += wA * __uint_as_float(pa << 16);
    a1 += wA * __uint_as_float(pa & 0xffff0000u);
    a2 += wB * __uint_as_float(pb << 16);
    a3 += wB * __uint_as_float(pb & 0xffff0000u);
  }
  float4 iS = *(const float4*)&invS[node * 4];
  float isA = hsel ? iS.y : iS.x;
  float isB = hsel ? iS.w : iS.z;
  float2 bA = *(const float2*)&bias[2 * lane];
  float2 bB = *(const float2*)&bias[128 + 2 * lane];
  float o0 = a0 * isA + bA.x;
  float o1 = a1 * isA + bA.y;
  float o2 = a2 * isB + bB.x;
  float o3 = a3 * isB + bB.y;
  o0 = o0 > 0.f ? o0 : (__expf(o0) - 1.0f);   // ELU (alpha=1)
  o1 = o1 > 0.f ? o1 : (__expf(o1) - 1.0f);
  o2 = o2 > 0.f ? o2 : (__expf(o2) - 1.0f);
  o3 = o3 > 0.f ? o3 : (__expf(o3) - 1.0f);
  u32* o32 = (u32*)out16;
  o32[(size_t)node * 128 + lane]      = (u32)f2bf_rn(o0) | ((u32)f2bf_rn(o1) << 16);
  o32[(size_t)node * 128 + 64 + lane] = (u32)f2bf_rn(o2) | ((u32)f2bf_rn(o3) << 16);
}

// ---------------- pooling + MLP ----------------

__global__ void bounds_kernel(const int* __restrict__ batch, int Nn, int* __restrict__ bounds) {
  int g = threadIdx.x;
  if (g > GG) return;
  int lo = 0, hi = Nn;
  while (lo < hi) { int mid = (lo + hi) >> 1; if (batch[mid] < g) lo = mid + 1; else hi = mid; }
  bounds[g] = lo;   // lower_bound of g; bounds[64] = N
}

// one wave per (graph, split); uint4 loads (1KB/wave-instr); lane = (rowpar, chunk)
__global__ __launch_bounds__(64) void pool_kernel(const u16* __restrict__ X,
    const int* __restrict__ bounds, float* __restrict__ pooled) {
  int g = blockIdx.x, split = blockIdx.y;
  int lane = threadIdx.x;                     // 64
  int s = bounds[g], e = bounds[g + 1];
  int cnt = e - s;
  if (cnt <= 0) return;
  int chunk = (cnt + gridDim.y - 1) / gridDim.y;
  int s2 = s + split * chunk, e2 = min(e, s2 + chunk);
  if (s2 >= e2) return;
  int r = lane >> 5, c = lane & 31;           // row parity, 16B chunk
  float acc[8] = {};
  for (int n = s2 + r; n < e2; n += 2) {
    uint4 v = *(const uint4*)&X[(size_t)n * HC + c * 8];
    acc[0] += __uint_as_float(v.x << 16);
    acc[1] += __uint_as_float(v.x & 0xffff0000u);
    acc[2] += __uint_as_float(v.y << 16);
    acc[3] += __uint_as_float(v.y & 0xffff0000u);
    acc[4] += __uint_as_float(v.z << 16);
    acc[5] += __uint_as_float(v.z & 0xffff0000u);
    acc[6] += __uint_as_float(v.w << 16);
    acc[7] += __uint_as_float(v.w & 0xffff0000u);
  }
  #pragma unroll
  for (int j = 0; j < 8; ++j) acc[j] += __shfl_xor(acc[j], 32, 64);
  if (r == 0) {
    #pragma unroll
    for (int j = 0; j < 8; ++j) atomicAdd(&pooled[g * HC + c * 8 + j], acc[j]);
  }
}

__global__ __launch_bounds__(512) void mlp_kernel(const float* __restrict__ pooled,
    const int* __restrict__ bounds, const float* __restrict__ Wp1, const float* __restrict__ bp1,
    const float* __restrict__ Wp2, const float* __restrict__ bp2, float* __restrict__ out) {
  __shared__ float p[256];
  __shared__ float z1[512];
  int g = blockIdx.x, t = threadIdx.x;
  if (t < 256) {
    int cnt = bounds[g + 1] - bounds[g];
    float inv = 1.0f / (float)(cnt > 1 ? cnt : 1);
    p[t] = pooled[g * 256 + t] * inv;
  }
  __syncthreads();
  float a1 = bp1[t];
  for (int k = 0; k < 256; ++k) a1 += p[k] * Wp1[k * 512 + t];
  z1[t] = fmaxf(a1, 0.f);
  __syncthreads();
  if (t < 256) {
    float a2 = bp2[t];
    for (int k = 0; k < 512; ++k) a2 += z1[k] * Wp2[k * 256 + t];
    out[g * 256 + t] = a2;
  }
}

// ---------------- launch ----------------

static inline size_t align_up(size_t x, size_t a) { return (x + a - 1) & ~(a - 1); }

extern "C" void kernel_launch(void* const* d_in, const int* in_sizes, int n_in,
                              void* d_out, int out_size, void* d_ws, size_t ws_size,
                              hipStream_t stream) {
  const float* x    = (const float*)d_in[0];
  const int*   ei   = (const int*)d_in[1];
  const int*   batch= (const int*)d_in[2];
  const float* W1   = (const float*)d_in[3];
  const float* a1s  = (const float*)d_in[4];
  const float* a1d  = (const float*)d_in[5];
  const float* b1   = (const float*)d_in[6];
  const float* W2   = (const float*)d_in[7];
  const float* a2s  = (const float*)d_in[8];
  const float* a2d  = (const float*)d_in[9];
  const float* b2   = (const float*)d_in[10];
  const float* W3   = (const float*)d_in[11];
  const float* a3s  = (const float*)d_in[12];
  const float* a3d  = (const float*)d_in[13];
  const float* b3   = (const float*)d_in[14];
  const float* Wp1  = (const float*)d_in[15];
  const float* bp1  = (const float*)d_in[16];
  const float* Wp2  = (const float*)d_in[17];
  const float* bp2  = (const float*)d_in[18];

  const int N = in_sizes[0] / 2;       // 100000
  const int E = in_sizes[1] / 2;       // 400000
  const int Et = E + N;                // with self loops

  char* base = (char*)d_ws;
  size_t off = 0;
  auto alloc = [&](size_t bytes) { size_t o = off; off = align_up(off + bytes, 256); return o; };
  u16*   h16    = (u16*)  (base + alloc((size_t)N * HC * 2));   // message-path h (bf16)
  u16*   xhi    = (u16*)  (base + alloc((size_t)N * HC * 2));   // gather out (bf16)
  float* als    = (float*)(base + alloc((size_t)N * 4 * 4));
  float* ald    = (float*)(base + alloc((size_t)N * 4 * 4));
  float* invS   = (float*)(base + alloc((size_t)N * 4 * 4));
  int*   rowptr = (int*)  (base + alloc((size_t)(N + 1) * 4));
  int*   col    = (int*)  (base + alloc((size_t)Et * 4));
  float* w      = (float*)(base + alloc((size_t)Et * 4 * 4));   // per-edge softmax numerators
  int*   deg    = (int*)  (base + alloc((size_t)N * 4));
  int*   cursor = (int*)  (base + alloc((size_t)N * 4));
  int*   bsum   = (int*)  (base + alloc(512 * 4));
  int*   bounds = (int*)  (base + alloc((GG + 1) * 4));
  float* pooled = (float*)(base + alloc((size_t)GG * HC * 4));
  (void)ws_size; (void)n_in; (void)out_size;

  // W2t/W3t (bf16, 128KB each) parked in deg/cursor space (dead after CSR build)
  u16* W2t = (u16*)deg;
  u16* W3t = (u16*)cursor;

  hipMemsetAsync(deg, 0, (size_t)N * 4, stream);
  hipMemsetAsync(cursor, 0, (size_t)N * 4, stream);
  hipMemsetAsync(pooled, 0, (size_t)GG * HC * 4, stream);

  // CSR by destination (same edge set for all layers)
  int ebk = (Et + 255) / 256;
  count_deg_kernel<<<ebk, 256, 0, stream>>>(ei, E, N, deg);
  int NT = (N + 255) / 256;
  scan_partial_kernel<<<NT, 256, 0, stream>>>(deg, N, rowptr, bsum);
  scan_bsum_kernel<<<1, 512, 0, stream>>>(bsum, NT);
  scan_add_kernel<<<NT, 256, 0, stream>>>(rowptr, bsum, N, Et);
  fill_csr_kernel<<<ebk, 256, 0, stream>>>(ei, E, N, rowptr, cursor, col);

  // weight conversion (deg/cursor now dead)
  convert_w_kernel<<<256, 256, 0, stream>>>(W2, W2t);
  convert_w_kernel<<<256, 256, 0, stream>>>(W3, W3t);

  dim3 gemm_grid(HC / GBN, (N + GBM - 1) / GBM);
  int nodeblk = (N + 3) / 4;

  // layer 1 (in=2, logits fused)
  gemm_k2_logits_kernel<<<nodeblk, 256, 0, stream>>>(x, W1, a1s, a1d, h16, als, ald, N);
  edge_softmax_kernel<<<NT, 256, 0, stream>>>(als, ald, rowptr, col, w, invS, N);
  gat_gather_kernel<<<nodeblk, 256, 0, stream>>>(h16, w, invS, rowptr, col, b1, xhi, N);
  // layer 2
  gemm_mfma_kernel<<<gemm_grid, 256, 0, stream>>>(xhi, W2t, a2s, a2d, h16, als, ald, N);
  edge_softmax_kernel<<<NT, 256, 0, stream>>>(als, ald, rowptr, col, w, invS, N);
  gat_gather_kernel<<<nodeblk, 256, 0, stream>>>(h16, w, invS, rowptr, col, b2, xhi, N);
  // layer 3
  gemm_mfma_kernel<<<gemm_grid, 256, 0, stream>>>(xhi, W3t, a3s, a3d, h16, als, ald, N);
  edge_softmax_kernel<<<NT, 256, 0, stream>>>(als, ald, rowptr, col, w, invS, N);
  gat_gather_kernel<<<nodeblk, 256, 0, stream>>>(h16, w, invS, rowptr, col, b3, xhi, N);

  // pool + MLP
  bounds_kernel<<<1, 128, 0, stream>>>(batch, N, bounds);
  pool_kernel<<<dim3(GG, 32), 64, 0, stream>>>(xhi, bounds, pooled);
  mlp_kernel<<<GG, 512, 0, stream>>>(pooled, bounds, Wp1, bp1, Wp2, bp2, (float*)d_out);
}

// Round 10
// 393.335 us; speedup vs baseline: 1.4933x; 1.1688x over previous
//
#include <hip/hip_runtime.h>
#include <math.h>

#define HC 256      // H*C
#define NHEAD 4
#define NEG_SLOPE 0.2f
#define GG 64       // graphs

typedef unsigned short u16;
typedef unsigned int u32;
typedef __attribute__((ext_vector_type(8))) short short8;
typedef __attribute__((ext_vector_type(4))) float f32x4;

static __device__ inline u16 f2bf_rn(float f) {
  u32 x = __float_as_uint(f);
  u32 r = (x + 0x7fffu + ((x >> 16) & 1u)) >> 16;
  return (u16)r;
}
static __device__ inline float bf2f(u16 u) { return __uint_as_float(((u32)u) << 16); }
static __device__ inline int swz(int b) { return b ^ (((b >> 8) & 7) << 4); }

// ---------------- CSR build ----------------

__global__ void count_deg_kernel(const int* __restrict__ ei, int E, int Nn, int* __restrict__ deg) {
  int idx = blockIdx.x * 256 + threadIdx.x;
  int Et = E + Nn;
  if (idx >= Et) return;
  int d = (idx < E) ? ei[E + idx] : (idx - E);   // row1 of edge_index = dst; self loops appended
  atomicAdd(&deg[d], 1);
}

__global__ void scan_partial_kernel(const int* __restrict__ deg, int Nn,
                                    int* __restrict__ rowptr, int* __restrict__ bsum) {
  __shared__ int s[256];
  int t = threadIdx.x, i = blockIdx.x * 256 + t;
  int v = (i < Nn) ? deg[i] : 0;
  s[t] = v; __syncthreads();
  for (int off = 1; off < 256; off <<= 1) {
    int x = (t >= off) ? s[t - off] : 0; __syncthreads();
    s[t] += x; __syncthreads();
  }
  if (i < Nn) rowptr[i] = s[t] - v;          // exclusive within block
  if (t == 255) bsum[blockIdx.x] = s[t];     // block total
}

__global__ void scan_bsum_kernel(int* __restrict__ bsum, int nb) {
  __shared__ int s[512];
  int t = threadIdx.x;
  int v = (t < nb) ? bsum[t] : 0;
  s[t] = v; __syncthreads();
  for (int off = 1; off < 512; off <<= 1) {
    int x = (t >= off) ? s[t - off] : 0; __syncthreads();
    s[t] += x; __syncthreads();
  }
  if (t < nb) bsum[t] = s[t] - v;            // exclusive block offsets
}

__global__ void scan_add_kernel(int* __restrict__ rowptr, const int* __restrict__ bsum,
                                int Nn, int Etot) {
  int i = blockIdx.x * 256 + threadIdx.x;
  if (i < Nn) rowptr[i] += bsum[blockIdx.x];
  if (i == 0) rowptr[Nn] = Etot;
}

__global__ void fill_csr_kernel(const int* __restrict__ ei, int E, int Nn,
                                const int* __restrict__ rowptr, int* __restrict__ cursor,
                                int* __restrict__ col) {
  int idx = blockIdx.x * 256 + threadIdx.x;
  int Et = E + Nn;
  if (idx >= Et) return;
  int s, d;
  if (idx < E) { s = ei[idx]; d = ei[E + idx]; } else { s = d = idx - E; }
  int pos = atomicAdd(&cursor[d], 1);
  col[rowptr[d] + pos] = s;
}

// ---------------- W transpose + bf16: Wt[n][k] ----------------

__global__ void convert_w_kernel(const float* __restrict__ W, u16* __restrict__ hi) {
  int idx = blockIdx.x * 256 + threadIdx.x;    // 65536 threads
  if (idx >= 256 * 256) return;
  int k = idx >> 8, n = idx & 255;             // coalesced read of W[k][n]
  hi[n * 256 + k] = f2bf_rn(W[idx]);
}

// ---------------- layer 1 (rank-2 factorization) ----------------
// va[k*4+q] = sum_{c in head q} W1[k][c]*a1s[c]; va[8+..] same with a1d.

__global__ void prep_va_kernel(const float* __restrict__ W1, const float* __restrict__ a1s,
                               const float* __restrict__ a1d, float* __restrict__ va) {
  int t = threadIdx.x;                       // 256 = 4 waves, wave q = head q
  int q = t >> 6, lane = t & 63;
  int c = t;
  float asv = a1s[c], adv = a1d[c];
  float w0 = W1[c], w1 = W1[256 + c];
  float s0 = w0 * asv, s1 = w1 * asv, d0 = w0 * adv, d1 = w1 * adv;
  #pragma unroll
  for (int off = 32; off >= 1; off >>= 1) {
    s0 += __shfl_xor(s0, off, 64); s1 += __shfl_xor(s1, off, 64);
    d0 += __shfl_xor(d0, off, 64); d1 += __shfl_xor(d1, off, 64);
  }
  if (lane == 0) {
    va[q] = s0; va[4 + q] = s1;
    va[8 + q] = d0; va[12 + q] = d1;
  }
}

// als/ald directly from x: als[q] = x0*va[q] + x1*va[4+q]
__global__ void logits1_kernel(const float* __restrict__ x, const float* __restrict__ va,
                               float* __restrict__ als, float* __restrict__ ald, int Nn) {
  int node = blockIdx.x * 256 + threadIdx.x;
  if (node >= Nn) return;
  float2 xv = *(const float2*)&x[(size_t)node * 2];
  float4 vs0 = *(const float4*)&va[0], vs1 = *(const float4*)&va[4];
  float4 vd0 = *(const float4*)&va[8], vd1 = *(const float4*)&va[12];
  float4 s, d;
  s.x = xv.x * vs0.x + xv.y * vs1.x; s.y = xv.x * vs0.y + xv.y * vs1.y;
  s.z = xv.x * vs0.z + xv.y * vs1.z; s.w = xv.x * vs0.w + xv.y * vs1.w;
  d.x = xv.x * vd0.x + xv.y * vd1.x; d.y = xv.x * vd0.y + xv.y * vd1.y;
  d.z = xv.x * vd0.z + xv.y * vd1.z; d.w = xv.x * vd0.w + xv.y * vd1.w;
  *(float4*)&als[node * 4] = s;
  *(float4*)&ald[node * 4] = d;
}

// fused max-free softmax + x-space gather: xbar[node][q*2+k] = (sum_e p^q_e x[s_e][k])/S_q
__global__ void sm_gather1_kernel(const float* __restrict__ x,
    const float* __restrict__ als, const float* __restrict__ ald,
    const int* __restrict__ rowptr, const int* __restrict__ col,
    float* __restrict__ xbar, int Nn) {
  int node = blockIdx.x * 256 + threadIdx.x;
  if (node >= Nn) return;
  int rs = rowptr[node], re = rowptr[node + 1];
  float4 ad = *(const float4*)&ald[node * 4];
  float S0 = 0.f, S1 = 0.f, S2 = 0.f, S3 = 0.f;
  float a0 = 0.f, a1 = 0.f, a2 = 0.f, a3 = 0.f, a4 = 0.f, a5 = 0.f, a6 = 0.f, a7 = 0.f;
  for (int i = rs; i < re; ++i) {
    int s = col[i];
    float4 a = *(const float4*)&als[(size_t)s * 4];
    float2 xs = *(const float2*)&x[(size_t)s * 2];
    float e0 = a.x + ad.x; e0 = e0 > 0.f ? e0 : NEG_SLOPE * e0;
    float e1 = a.y + ad.y; e1 = e1 > 0.f ? e1 : NEG_SLOPE * e1;
    float e2 = a.z + ad.z; e2 = e2 > 0.f ? e2 : NEG_SLOPE * e2;
    float e3 = a.w + ad.w; e3 = e3 > 0.f ? e3 : NEG_SLOPE * e3;
    float p0 = __expf(e0), p1 = __expf(e1), p2 = __expf(e2), p3 = __expf(e3);
    S0 += p0; S1 += p1; S2 += p2; S3 += p3;
    a0 += p0 * xs.x; a1 += p0 * xs.y;
    a2 += p1 * xs.x; a3 += p1 * xs.y;
    a4 += p2 * xs.x; a5 += p2 * xs.y;
    a6 += p3 * xs.x; a7 += p3 * xs.y;
  }
  float i0 = 1.f / (S0 + 1e-16f), i1 = 1.f / (S1 + 1e-16f);
  float i2 = 1.f / (S2 + 1e-16f), i3 = 1.f / (S3 + 1e-16f);
  *(float4*)&xbar[(size_t)node * 8]     = make_float4(a0 * i0, a1 * i0, a2 * i1, a3 * i1);
  *(float4*)&xbar[(size_t)node * 8 + 4] = make_float4(a4 * i2, a5 * i2, a6 * i3, a7 * i3);
}

// expand: out1[node][c] = xbar_q . W1[:,c] + b1[c], ELU, bf16-packed
// wave per node; lane owns ch {2l, 2l+1, 128+2l, 128+2l+1} (same layout as gather v3)
__global__ __launch_bounds__(256) void expand1_kernel(const float* __restrict__ xbar,
    const float* __restrict__ W1, const float* __restrict__ b1,
    u16* __restrict__ out16, int Nn) {
  int node = blockIdx.x * 4 + (threadIdx.x >> 6);
  int lane = threadIdx.x & 63;
  if (node >= Nn) return;
  int hA = lane >> 5;                        // head of ch pair A (0/1); pair B head = 2+hA
  float4 xb0 = *(const float4*)&xbar[(size_t)node * 8];      // heads 0,1
  float4 xb1 = *(const float4*)&xbar[(size_t)node * 8 + 4];  // heads 2,3
  float xA0 = hA ? xb0.z : xb0.x, xA1 = hA ? xb0.w : xb0.y;
  float xB0 = hA ? xb1.z : xb1.x, xB1 = hA ? xb1.w : xb1.y;
  int cA = 2 * lane, cB = 128 + 2 * lane;
  float2 wA0 = *(const float2*)&W1[cA], wA1 = *(const float2*)&W1[256 + cA];
  float2 wB0 = *(const float2*)&W1[cB], wB1 = *(const float2*)&W1[256 + cB];
  float2 bA = *(const float2*)&b1[cA],  bB = *(const float2*)&b1[cB];
  float o0 = xA0 * wA0.x + xA1 * wA1.x + bA.x;
  float o1 = xA0 * wA0.y + xA1 * wA1.y + bA.y;
  float o2 = xB0 * wB0.x + xB1 * wB1.x + bB.x;
  float o3 = xB0 * wB0.y + xB1 * wB1.y + bB.y;
  o0 = o0 > 0.f ? o0 : (__expf(o0) - 1.0f);
  o1 = o1 > 0.f ? o1 : (__expf(o1) - 1.0f);
  o2 = o2 > 0.f ? o2 : (__expf(o2) - 1.0f);
  o3 = o3 > 0.f ? o3 : (__expf(o3) - 1.0f);
  u32* o32 = (u32*)out16;
  o32[(size_t)node * 128 + lane]      = (u32)f2bf_rn(o0) | ((u32)f2bf_rn(o1) << 16);
  o32[(size_t)node * 128 + 64 + lane] = (u32)f2bf_rn(o2) | ((u32)f2bf_rn(o3) << 16);
}

// ---------------- pipelined LDS MFMA GEMM (2-phase, T14 issue-early) ----------------

#define GBM 128
#define GBN 128

__global__ __launch_bounds__(256) void gemm_mfma_kernel(
    const u16* __restrict__ A, const u16* __restrict__ Bt,
    const float* __restrict__ as_, const float* __restrict__ ad_,
    u16* __restrict__ C16, float* __restrict__ als, float* __restrict__ ald, int Mrows) {
  __shared__ __align__(16) u16 sA[2][4096];   // 2 x 8KB
  __shared__ __align__(16) u16 sB[2][4096];   // 2 x 8KB
  char* sAc = (char*)&sA[0][0];
  char* sBc = (char*)&sB[0][0];
  int bc = blockIdx.x, br = blockIdx.y;
  int tid = threadIdx.x;
  int wid = tid >> 6, lane = tid & 63;
  int wr = wid >> 1, wc = wid & 1;             // 2x2 waves; each 64x64 output
  int row0 = br * GBM, col0 = bc * GBN;
  int fr = lane & 15, fg = lane >> 4;

  const u16* agp[2];
  const u16* bgp[2];
  int wof[2];
  #pragma unroll
  for (int j = 0; j < 2; ++j) {
    int rr = wid * 32 + j * 16 + (lane >> 2);
    int kc = lane & 3;
    int gr = row0 + rr; if (gr >= Mrows) gr = Mrows - 1;
    agp[j] = A + (size_t)gr * 256 + kc * 8;
    bgp[j] = Bt + (size_t)(col0 + rr) * 256 + kc * 8;
    wof[j] = swz(rr * 64 + kc * 16);
  }
  int rofA[4], rofB[4];
  #pragma unroll
  for (int m = 0; m < 4; ++m) rofA[m] = swz((wr * 64 + m * 16 + fr) * 64 + fg * 16);
  #pragma unroll
  for (int n = 0; n < 4; ++n) rofB[n] = swz((wc * 64 + n * 16 + fr) * 64 + fg * 16);

  f32x4 acc[4][4];
  #pragma unroll
  for (int m = 0; m < 4; ++m)
    #pragma unroll
    for (int n = 0; n < 4; ++n) acc[m][n] = (f32x4){0.f, 0.f, 0.f, 0.f};

  uint4 va[2], vb[2];
  #pragma unroll
  for (int j = 0; j < 2; ++j) { va[j] = *(const uint4*)agp[j]; vb[j] = *(const uint4*)bgp[j]; }
  #pragma unroll
  for (int j = 0; j < 2; ++j) {
    *(uint4*)(sAc + wof[j]) = va[j];
    *(uint4*)(sBc + wof[j]) = vb[j];
  }
  __syncthreads();

  #pragma unroll
  for (int kt = 0; kt < 8; ++kt) {             // K = 8 x 32
    int buf = kt & 1;
    if (kt < 7) {                              // T14: issue next-tile loads early
      #pragma unroll
      for (int j = 0; j < 2; ++j) {
        va[j] = *(const uint4*)(agp[j] + (kt + 1) * 32);
        vb[j] = *(const uint4*)(bgp[j] + (kt + 1) * 32);
      }
    }
    short8 af[4], bf[4];
    #pragma unroll
    for (int m = 0; m < 4; ++m) af[m] = *(const short8*)(sAc + buf * 8192 + rofA[m]);
    #pragma unroll
    for (int n = 0; n < 4; ++n) bf[n] = *(const short8*)(sBc + buf * 8192 + rofB[n]);
    #pragma unroll
    for (int m = 0; m < 4; ++m)
      #pragma unroll
      for (int n = 0; n < 4; ++n)
        acc[m][n] = __builtin_amdgcn_mfma_f32_16x16x32_bf16(af[m], bf[n], acc[m][n], 0, 0, 0);
    if (kt < 7) {                              // write next buffer, one barrier
      int nb = buf ^ 1;
      #pragma unroll
      for (int j = 0; j < 2; ++j) {
        *(uint4*)(sAc + nb * 8192 + wof[j]) = va[j];
        *(uint4*)(sBc + nb * 8192 + wof[j]) = vb[j];
      }
      __syncthreads();
    }
  }

  // C write (bf16): col=lane&15 within frag, row=(lane>>4)*4+j
  #pragma unroll
  for (int m = 0; m < 4; ++m) {
    #pragma unroll
    for (int n = 0; n < 4; ++n) {
      int col = col0 + wc * 64 + n * 16 + fr;
      #pragma unroll
      for (int j = 0; j < 4; ++j) {
        int row = row0 + wr * 64 + m * 16 + fg * 4 + j;
        if (row < Mrows) C16[(size_t)row * 256 + col] = f2bf_rn(acc[m][n][j]);
      }
    }
  }

  // fused logits: this wave's 64 cols = one head
  int head = bc * 2 + wc;
  float asv[4], adv[4];
  #pragma unroll
  for (int n = 0; n < 4; ++n) {
    asv[n] = as_[head * 64 + n * 16 + fr];
    adv[n] = ad_[head * 64 + n * 16 + fr];
  }
  #pragma unroll
  for (int m = 0; m < 4; ++m) {
    #pragma unroll
    for (int j = 0; j < 4; ++j) {
      float ps = 0.f, pd = 0.f;
      #pragma unroll
      for (int n = 0; n < 4; ++n) {
        ps += acc[m][n][j] * asv[n];
        pd += acc[m][n][j] * adv[n];
      }
      #pragma unroll
      for (int off = 1; off < 16; off <<= 1) {
        ps += __shfl_xor(ps, off, 64);
        pd += __shfl_xor(pd, off, 64);
      }
      int grow = row0 + wr * 64 + m * 16 + fg * 4 + j;
      if (fr == 0 && grow < Mrows) {
        als[grow * 4 + head] = ps;
        ald[grow * 4 + head] = pd;
      }
    }
  }
}

// ---------------- edge softmax: single pass, max-free ----------------

__global__ void edge_softmax_kernel(const float* __restrict__ als, const float* __restrict__ ald,
                                    const int* __restrict__ rowptr, const int* __restrict__ col,
                                    float* __restrict__ w, float* __restrict__ invS, int Nn) {
  int node = blockIdx.x * 256 + threadIdx.x;
  if (node >= Nn) return;
  int rs = rowptr[node], re = rowptr[node + 1];
  float4 ad = *(const float4*)&ald[node * 4];
  float S0 = 0.f, S1 = 0.f, S2 = 0.f, S3 = 0.f;
  for (int i = rs; i < re; ++i) {
    int s = col[i];
    float4 a = *(const float4*)&als[(size_t)s * 4];
    float e0 = a.x + ad.x; e0 = e0 > 0.f ? e0 : NEG_SLOPE * e0;
    float e1 = a.y + ad.y; e1 = e1 > 0.f ? e1 : NEG_SLOPE * e1;
    float e2 = a.z + ad.z; e2 = e2 > 0.f ? e2 : NEG_SLOPE * e2;
    float e3 = a.w + ad.w; e3 = e3 > 0.f ? e3 : NEG_SLOPE * e3;
    float p0 = __expf(e0), p1 = __expf(e1), p2 = __expf(e2), p3 = __expf(e3);
    *(float4*)&w[(size_t)i * 4] = make_float4(p0, p1, p2, p3);
    S0 += p0; S1 += p1; S2 += p2; S3 += p3;
  }
  *(float4*)&invS[node * 4] = make_float4(1.f / (S0 + 1e-16f), 1.f / (S1 + 1e-16f),
                                          1.f / (S2 + 1e-16f), 1.f / (S3 + 1e-16f));
}

// ---------------- GAT gather v3: weighted sum, channel-pair dwords ----------------

__global__ __launch_bounds__(256) void gat_gather_kernel(const u16* __restrict__ h16,
    const float* __restrict__ w, const float* __restrict__ invS,
    const int* __restrict__ rowptr, const int* __restrict__ col,
    const float* __restrict__ bias, u16* __restrict__ out16, int Nn) {
  int node = __builtin_amdgcn_readfirstlane(blockIdx.x * 4 + (threadIdx.x >> 6));
  int lane = threadIdx.x & 63;
  if (node >= Nn) return;
  int rs = rowptr[node], re = rowptr[node + 1];
  int hsel = lane >> 5;                       // head parity selector
  float a0 = 0.f, a1 = 0.f, a2 = 0.f, a3 = 0.f;
  const u32* h32 = (const u32*)h16;
  for (int i = rs; i < re; ++i) {
    int s = col[i];
    float4 wv = *(const float4*)&w[(size_t)i * 4];
    float wA = hsel ? wv.y : wv.x;
    float wB = hsel ? wv.w : wv.z;
    const u32* hr = h32 + (size_t)s * 128;
    u32 pa = hr[lane];                        // ch 2l, 2l+1   (head l>>5)
    u32 pb = hr[64 + lane];                   // ch 128+2l, 128+2l+1 (head 2+(l>>5))
    a0 += wA * __uint_as_float(pa << 16);
    a1 += wA * __uint_as_float(pa & 0xffff0000u);
    a2 += wB * __uint_as_float(pb << 16);
    a3 += wB * __uint_as_float(pb & 0xffff0000u);
  }
  float4 iS = *(const float4*)&invS[node * 4];
  float isA = hsel ? iS.y : iS.x;
  float isB = hsel ? iS.w : iS.z;
  float2 bA = *(const float2*)&bias[2 * lane];
  float2 bB = *(const float2*)&bias[128 + 2 * lane];
  float o0 = a0 * isA + bA.x;
  float o1 = a1 * isA + bA.y;
  float o2 = a2 * isB + bB.x;
  float o3 = a3 * isB + bB.y;
  o0 = o0 > 0.f ? o0 : (__expf(o0) - 1.0f);   // ELU (alpha=1)
  o1 = o1 > 0.f ? o1 : (__expf(o1) - 1.0f);
  o2 = o2 > 0.f ? o2 : (__expf(o2) - 1.0f);
  o3 = o3 > 0.f ? o3 : (__expf(o3) - 1.0f);
  u32* o32 = (u32*)out16;
  o32[(size_t)node * 128 + lane]      = (u32)f2bf_rn(o0) | ((u32)f2bf_rn(o1) << 16);
  o32[(size_t)node * 128 + 64 + lane] = (u32)f2bf_rn(o2) | ((u32)f2bf_rn(o3) << 16);
}

// ---------------- pooling + MLP ----------------

__global__ void bounds_kernel(const int* __restrict__ batch, int Nn, int* __restrict__ bounds) {
  int g = threadIdx.x;
  if (g > GG) return;
  int lo = 0, hi = Nn;
  while (lo < hi) { int mid = (lo + hi) >> 1; if (batch[mid] < g) lo = mid + 1; else hi = mid; }
  bounds[g] = lo;   // lower_bound of g; bounds[64] = N
}

// one wave per (graph, split); uint4 loads (1KB/wave-instr); lane = (rowpar, chunk)
__global__ __launch_bounds__(64) void pool_kernel(const u16* __restrict__ X,
    const int* __restrict__ bounds, float* __restrict__ pooled) {
  int g = blockIdx.x, split = blockIdx.y;
  int lane = threadIdx.x;                     // 64
  int s = bounds[g], e = bounds[g + 1];
  int cnt = e - s;
  if (cnt <= 0) return;
  int chunk = (cnt + gridDim.y - 1) / gridDim.y;
  int s2 = s + split * chunk, e2 = min(e, s2 + chunk);
  if (s2 >= e2) return;
  int r = lane >> 5, c = lane & 31;           // row parity, 16B chunk
  float acc[8] = {};
  for (int n = s2 + r; n < e2; n += 2) {
    uint4 v = *(const uint4*)&X[(size_t)n * HC + c * 8];
    acc[0] += __uint_as_float(v.x << 16);
    acc[1] += __uint_as_float(v.x & 0xffff0000u);
    acc[2] += __uint_as_float(v.y << 16);
    acc[3] += __uint_as_float(v.y & 0xffff0000u);
    acc[4] += __uint_as_float(v.z << 16);
    acc[5] += __uint_as_float(v.z & 0xffff0000u);
    acc[6] += __uint_as_float(v.w << 16);
    acc[7] += __uint_as_float(v.w & 0xffff0000u);
  }
  #pragma unroll
  for (int j = 0; j < 8; ++j) acc[j] += __shfl_xor(acc[j], 32, 64);
  if (r == 0) {
    #pragma unroll
    for (int j = 0; j < 8; ++j) atomicAdd(&pooled[g * HC + c * 8 + j], acc[j]);
  }
}

__global__ __launch_bounds__(512) void mlp_kernel(const float* __restrict__ pooled,
    const int* __restrict__ bounds, const float* __restrict__ Wp1, const float* __restrict__ bp1,
    const float* __restrict__ Wp2, const float* __restrict__ bp2, float* __restrict__ out) {
  __shared__ float p[256];
  __shared__ float z1[512];
  int g = blockIdx.x, t = threadIdx.x;
  if (t < 256) {
    int cnt = bounds[g + 1] - bounds[g];
    float inv = 1.0f / (float)(cnt > 1 ? cnt : 1);
    p[t] = pooled[g * 256 + t] * inv;
  }
  __syncthreads();
  float a1 = bp1[t];
  for (int k = 0; k < 256; ++k) a1 += p[k] * Wp1[k * 512 + t];
  z1[t] = fmaxf(a1, 0.f);
  __syncthreads();
  if (t < 256) {
    float a2 = bp2[t];
    for (int k = 0; k < 512; ++k) a2 += z1[k] * Wp2[k * 256 + t];
    out[g * 256 + t] = a2;
  }
}

// ---------------- launch ----------------

static inline size_t align_up(size_t x, size_t a) { return (x + a - 1) & ~(a - 1); }

extern "C" void kernel_launch(void* const* d_in, const int* in_sizes, int n_in,
                              void* d_out, int out_size, void* d_ws, size_t ws_size,
                              hipStream_t stream) {
  const float* x    = (const float*)d_in[0];
  const int*   ei   = (const int*)d_in[1];
  const int*   batch= (const int*)d_in[2];
  const float* W1   = (const float*)d_in[3];
  const float* a1s  = (const float*)d_in[4];
  const float* a1d  = (const float*)d_in[5];
  const float* b1   = (const float*)d_in[6];
  const float* W2   = (const float*)d_in[7];
  const float* a2s  = (const float*)d_in[8];
  const float* a2d  = (const float*)d_in[9];
  const float* b2   = (const float*)d_in[10];
  const float* W3   = (const float*)d_in[11];
  const float* a3s  = (const float*)d_in[12];
  const float* a3d  = (const float*)d_in[13];
  const float* b3   = (const float*)d_in[14];
  const float* Wp1  = (const float*)d_in[15];
  const float* bp1  = (const float*)d_in[16];
  const float* Wp2  = (const float*)d_in[17];
  const float* bp2  = (const float*)d_in[18];

  const int N = in_sizes[0] / 2;       // 100000
  const int E = in_sizes[1] / 2;       // 400000
  const int Et = E + N;                // with self loops

  char* base = (char*)d_ws;
  size_t off = 0;
  auto alloc = [&](size_t bytes) { size_t o = off; off = align_up(off + bytes, 256); return o; };
  u16*   h16    = (u16*)  (base + alloc((size_t)N * HC * 2));   // message-path h (bf16)
  u16*   xhi    = (u16*)  (base + alloc((size_t)N * HC * 2));   // gather out (bf16)
  float* als    = (float*)(base + alloc((size_t)N * 4 * 4));
  float* ald    = (float*)(base + alloc((size_t)N * 4 * 4));
  float* invS   = (float*)(base + alloc((size_t)N * 4 * 4));
  float* xbar   = (float*)(base + alloc((size_t)N * 8 * 4));    // layer-1 x-space gather
  float* vabuf  = (float*)(base + alloc(16 * 4));
  int*   rowptr = (int*)  (base + alloc((size_t)(N + 1) * 4));
  int*   col    = (int*)  (base + alloc((size_t)Et * 4));
  float* w      = (float*)(base + alloc((size_t)Et * 4 * 4));   // per-edge softmax numerators
  int*   deg    = (int*)  (base + alloc((size_t)N * 4));
  int*   cursor = (int*)  (base + alloc((size_t)N * 4));
  int*   bsum   = (int*)  (base + alloc(512 * 4));
  int*   bounds = (int*)  (base + alloc((GG + 1) * 4));
  float* pooled = (float*)(base + alloc((size_t)GG * HC * 4));
  (void)ws_size; (void)n_in; (void)out_size;

  // W2t/W3t (bf16, 128KB each) parked in deg/cursor space (dead after CSR build)
  u16* W2t = (u16*)deg;
  u16* W3t = (u16*)cursor;

  hipMemsetAsync(deg, 0, (size_t)N * 4, stream);
  hipMemsetAsync(cursor, 0, (size_t)N * 4, stream);
  hipMemsetAsync(pooled, 0, (size_t)GG * HC * 4, stream);

  // CSR by destination (same edge set for all layers)
  int ebk = (Et + 255) / 256;
  count_deg_kernel<<<ebk, 256, 0, stream>>>(ei, E, N, deg);
  int NT = (N + 255) / 256;
  scan_partial_kernel<<<NT, 256, 0, stream>>>(deg, N, rowptr, bsum);
  scan_bsum_kernel<<<1, 512, 0, stream>>>(bsum, NT);
  scan_add_kernel<<<NT, 256, 0, stream>>>(rowptr, bsum, N, Et);
  fill_csr_kernel<<<ebk, 256, 0, stream>>>(ei, E, N, rowptr, cursor, col);

  // weight conversion (deg/cursor now dead)
  convert_w_kernel<<<256, 256, 0, stream>>>(W2, W2t);
  convert_w_kernel<<<256, 256, 0, stream>>>(W3, W3t);

  dim3 gemm_grid(HC / GBN, (N + GBM - 1) / GBM);
  int nodeblk = (N + 3) / 4;

  // layer 1 — rank-2 factorization: everything in x-space, then one expand
  prep_va_kernel<<<1, 256, 0, stream>>>(W1, a1s, a1d, vabuf);
  logits1_kernel<<<NT, 256, 0, stream>>>(x, vabuf, als, ald, N);
  sm_gather1_kernel<<<NT, 256, 0, stream>>>(x, als, ald, rowptr, col, xbar, N);
  expand1_kernel<<<nodeblk, 256, 0, stream>>>(xbar, W1, b1, xhi, N);
  // layer 2
  gemm_mfma_kernel<<<gemm_grid, 256, 0, stream>>>(xhi, W2t, a2s, a2d, h16, als, ald, N);
  edge_softmax_kernel<<<NT, 256, 0, stream>>>(als, ald, rowptr, col, w, invS, N);
  gat_gather_kernel<<<nodeblk, 256, 0, stream>>>(h16, w, invS, rowptr, col, b2, xhi, N);
  // layer 3
  gemm_mfma_kernel<<<gemm_grid, 256, 0, stream>>>(xhi, W3t, a3s, a3d, h16, als, ald, N);
  edge_softmax_kernel<<<NT, 256, 0, stream>>>(als, ald, rowptr, col, w, invS, N);
  gat_gather_kernel<<<nodeblk, 256, 0, stream>>>(h16, w, invS, rowptr, col, b3, xhi, N);

  // pool + MLP
  bounds_kernel<<<1, 128, 0, stream>>>(batch, N, bounds);
  pool_kernel<<<dim3(GG, 32), 64, 0, stream>>>(xhi, bounds, pooled);
  mlp_kernel<<<GG, 512, 0, stream>>>(pooled, bounds, Wp1, bp1, Wp2, bp2, (float*)d_out);
}

// Round 11
// 381.639 us; speedup vs baseline: 1.5390x; 1.0306x over previous
//
#include <hip/hip_runtime.h>
#include <math.h>

#define HC 256      // H*C
#define NHEAD 4
#define NEG_SLOPE 0.2f
#define GG 64       // graphs

typedef unsigned short u16;
typedef unsigned int u32;
typedef __attribute__((ext_vector_type(8))) short short8;
typedef __attribute__((ext_vector_type(4))) float f32x4;

static __device__ inline u16 f2bf_rn(float f) {
  u32 x = __float_as_uint(f);
  u32 r = (x + 0x7fffu + ((x >> 16) & 1u)) >> 16;
  return (u16)r;
}
static __device__ inline float bf2f(u16 u) { return __uint_as_float(((u32)u) << 16); }
static __device__ inline int swz(int b) { return b ^ (((b >> 8) & 7) << 4); }

// ---------------- CSR build ----------------

__global__ void count_deg_kernel(const int* __restrict__ ei, int E, int Nn, int* __restrict__ deg) {
  int idx = blockIdx.x * 256 + threadIdx.x;
  int Et = E + Nn;
  if (idx >= Et) return;
  int d = (idx < E) ? ei[E + idx] : (idx - E);   // row1 of edge_index = dst; self loops appended
  atomicAdd(&deg[d], 1);
}

__global__ void scan_partial_kernel(const int* __restrict__ deg, int Nn,
                                    int* __restrict__ rowptr, int* __restrict__ bsum) {
  __shared__ int s[256];
  int t = threadIdx.x, i = blockIdx.x * 256 + t;
  int v = (i < Nn) ? deg[i] : 0;
  s[t] = v; __syncthreads();
  for (int off = 1; off < 256; off <<= 1) {
    int x = (t >= off) ? s[t - off] : 0; __syncthreads();
    s[t] += x; __syncthreads();
  }
  if (i < Nn) rowptr[i] = s[t] - v;          // exclusive within block
  if (t == 255) bsum[blockIdx.x] = s[t];     // block total
}

__global__ void scan_bsum_kernel(int* __restrict__ bsum, int nb) {
  __shared__ int s[512];
  int t = threadIdx.x;
  int v = (t < nb) ? bsum[t] : 0;
  s[t] = v; __syncthreads();
  for (int off = 1; off < 512; off <<= 1) {
    int x = (t >= off) ? s[t - off] : 0; __syncthreads();
    s[t] += x; __syncthreads();
  }
  if (t < nb) bsum[t] = s[t] - v;            // exclusive block offsets
}

__global__ void scan_add_kernel(int* __restrict__ rowptr, const int* __restrict__ bsum,
                                int Nn, int Etot) {
  int i = blockIdx.x * 256 + threadIdx.x;
  if (i < Nn) rowptr[i] += bsum[blockIdx.x];
  if (i == 0) rowptr[Nn] = Etot;
}

__global__ void fill_csr_kernel(const int* __restrict__ ei, int E, int Nn,
                                const int* __restrict__ rowptr, int* __restrict__ cursor,
                                int* __restrict__ col) {
  int idx = blockIdx.x * 256 + threadIdx.x;
  int Et = E + Nn;
  if (idx >= Et) return;
  int s, d;
  if (idx < E) { s = ei[idx]; d = ei[E + idx]; } else { s = d = idx - E; }
  int pos = atomicAdd(&cursor[d], 1);
  col[rowptr[d] + pos] = s;
}

// ---------------- W transpose + bf16: Wt[n][k] ----------------

__global__ void convert_w_kernel(const float* __restrict__ W, u16* __restrict__ hi) {
  int idx = blockIdx.x * 256 + threadIdx.x;    // 65536 threads
  if (idx >= 256 * 256) return;
  int k = idx >> 8, n = idx & 255;             // coalesced read of W[k][n]
  hi[n * 256 + k] = f2bf_rn(W[idx]);
}

// ---------------- layer 1 (rank-2 factorization) ----------------
// va[k*4+q] = sum_{c in head q} W1[k][c]*a1s[c]; va[8+..] same with a1d.

__global__ void prep_va_kernel(const float* __restrict__ W1, const float* __restrict__ a1s,
                               const float* __restrict__ a1d, float* __restrict__ va) {
  int t = threadIdx.x;                       // 256 = 4 waves, wave q = head q
  int q = t >> 6, lane = t & 63;
  int c = t;
  float asv = a1s[c], adv = a1d[c];
  float w0 = W1[c], w1 = W1[256 + c];
  float s0 = w0 * asv, s1 = w1 * asv, d0 = w0 * adv, d1 = w1 * adv;
  #pragma unroll
  for (int off = 32; off >= 1; off >>= 1) {
    s0 += __shfl_xor(s0, off, 64); s1 += __shfl_xor(s1, off, 64);
    d0 += __shfl_xor(d0, off, 64); d1 += __shfl_xor(d1, off, 64);
  }
  if (lane == 0) {
    va[q] = s0; va[4 + q] = s1;
    va[8 + q] = d0; va[12 + q] = d1;
  }
}

// als/ald directly from x: als[q] = x0*va[q] + x1*va[4+q]
__global__ void logits1_kernel(const float* __restrict__ x, const float* __restrict__ va,
                               float* __restrict__ als, float* __restrict__ ald, int Nn) {
  int node = blockIdx.x * 256 + threadIdx.x;
  if (node >= Nn) return;
  float2 xv = *(const float2*)&x[(size_t)node * 2];
  float4 vs0 = *(const float4*)&va[0], vs1 = *(const float4*)&va[4];
  float4 vd0 = *(const float4*)&va[8], vd1 = *(const float4*)&va[12];
  float4 s, d;
  s.x = xv.x * vs0.x + xv.y * vs1.x; s.y = xv.x * vs0.y + xv.y * vs1.y;
  s.z = xv.x * vs0.z + xv.y * vs1.z; s.w = xv.x * vs0.w + xv.y * vs1.w;
  d.x = xv.x * vd0.x + xv.y * vd1.x; d.y = xv.x * vd0.y + xv.y * vd1.y;
  d.z = xv.x * vd0.z + xv.y * vd1.z; d.w = xv.x * vd0.w + xv.y * vd1.w;
  *(float4*)&als[node * 4] = s;
  *(float4*)&ald[node * 4] = d;
}

// fused max-free softmax + x-space gather: xbar[node][q*2+k] = (sum_e p^q_e x[s_e][k])/S_q
__global__ void sm_gather1_kernel(const float* __restrict__ x,
    const float* __restrict__ als, const float* __restrict__ ald,
    const int* __restrict__ rowptr, const int* __restrict__ col,
    float* __restrict__ xbar, int Nn) {
  int node = blockIdx.x * 256 + threadIdx.x;
  if (node >= Nn) return;
  int rs = rowptr[node], re = rowptr[node + 1];
  float4 ad = *(const float4*)&ald[node * 4];
  float S0 = 0.f, S1 = 0.f, S2 = 0.f, S3 = 0.f;
  float a0 = 0.f, a1 = 0.f, a2 = 0.f, a3 = 0.f, a4 = 0.f, a5 = 0.f, a6 = 0.f, a7 = 0.f;
  for (int i = rs; i < re; ++i) {
    int s = col[i];
    float4 a = *(const float4*)&als[(size_t)s * 4];
    float2 xs = *(const float2*)&x[(size_t)s * 2];
    float e0 = a.x + ad.x; e0 = e0 > 0.f ? e0 : NEG_SLOPE * e0;
    float e1 = a.y + ad.y; e1 = e1 > 0.f ? e1 : NEG_SLOPE * e1;
    float e2 = a.z + ad.z; e2 = e2 > 0.f ? e2 : NEG_SLOPE * e2;
    float e3 = a.w + ad.w; e3 = e3 > 0.f ? e3 : NEG_SLOPE * e3;
    float p0 = __expf(e0), p1 = __expf(e1), p2 = __expf(e2), p3 = __expf(e3);
    S0 += p0; S1 += p1; S2 += p2; S3 += p3;
    a0 += p0 * xs.x; a1 += p0 * xs.y;
    a2 += p1 * xs.x; a3 += p1 * xs.y;
    a4 += p2 * xs.x; a5 += p2 * xs.y;
    a6 += p3 * xs.x; a7 += p3 * xs.y;
  }
  float i0 = 1.f / (S0 + 1e-16f), i1 = 1.f / (S1 + 1e-16f);
  float i2 = 1.f / (S2 + 1e-16f), i3 = 1.f / (S3 + 1e-16f);
  *(float4*)&xbar[(size_t)node * 8]     = make_float4(a0 * i0, a1 * i0, a2 * i1, a3 * i1);
  *(float4*)&xbar[(size_t)node * 8 + 4] = make_float4(a4 * i2, a5 * i2, a6 * i3, a7 * i3);
}

// expand: out1[node][c] = xbar_q . W1[:,c] + b1[c], ELU, bf16-packed
// wave per node; lane owns ch {2l, 2l+1, 128+2l, 128+2l+1} (same layout as gather v3)
__global__ __launch_bounds__(256) void expand1_kernel(const float* __restrict__ xbar,
    const float* __restrict__ W1, const float* __restrict__ b1,
    u16* __restrict__ out16, int Nn) {
  int node = blockIdx.x * 4 + (threadIdx.x >> 6);
  int lane = threadIdx.x & 63;
  if (node >= Nn) return;
  int hA = lane >> 5;                        // head of ch pair A (0/1); pair B head = 2+hA
  float4 xb0 = *(const float4*)&xbar[(size_t)node * 8];      // heads 0,1
  float4 xb1 = *(const float4*)&xbar[(size_t)node * 8 + 4];  // heads 2,3
  float xA0 = hA ? xb0.z : xb0.x, xA1 = hA ? xb0.w : xb0.y;
  float xB0 = hA ? xb1.z : xb1.x, xB1 = hA ? xb1.w : xb1.y;
  int cA = 2 * lane, cB = 128 + 2 * lane;
  float2 wA0 = *(const float2*)&W1[cA], wA1 = *(const float2*)&W1[256 + cA];
  float2 wB0 = *(const float2*)&W1[cB], wB1 = *(const float2*)&W1[256 + cB];
  float2 bA = *(const float2*)&b1[cA],  bB = *(const float2*)&b1[cB];
  float o0 = xA0 * wA0.x + xA1 * wA1.x + bA.x;
  float o1 = xA0 * wA0.y + xA1 * wA1.y + bA.y;
  float o2 = xB0 * wB0.x + xB1 * wB1.x + bB.x;
  float o3 = xB0 * wB0.y + xB1 * wB1.y + bB.y;
  o0 = o0 > 0.f ? o0 : (__expf(o0) - 1.0f);
  o1 = o1 > 0.f ? o1 : (__expf(o1) - 1.0f);
  o2 = o2 > 0.f ? o2 : (__expf(o2) - 1.0f);
  o3 = o3 > 0.f ? o3 : (__expf(o3) - 1.0f);
  u32* o32 = (u32*)out16;
  o32[(size_t)node * 128 + lane]      = (u32)f2bf_rn(o0) | ((u32)f2bf_rn(o1) << 16);
  o32[(size_t)node * 128 + 64 + lane] = (u32)f2bf_rn(o2) | ((u32)f2bf_rn(o3) << 16);
}

// ---------------- pipelined LDS MFMA GEMM (2-phase, T14 issue-early) ----------------

#define GBM 128
#define GBN 128

__global__ __launch_bounds__(256) void gemm_mfma_kernel(
    const u16* __restrict__ A, const u16* __restrict__ Bt,
    const float* __restrict__ as_, const float* __restrict__ ad_,
    u16* __restrict__ C16, float* __restrict__ als, float* __restrict__ ald, int Mrows) {
  __shared__ __align__(16) u16 sA[2][4096];   // 2 x 8KB
  __shared__ __align__(16) u16 sB[2][4096];   // 2 x 8KB
  char* sAc = (char*)&sA[0][0];
  char* sBc = (char*)&sB[0][0];
  int bc = blockIdx.x, br = blockIdx.y;
  int tid = threadIdx.x;
  int wid = tid >> 6, lane = tid & 63;
  int wr = wid >> 1, wc = wid & 1;             // 2x2 waves; each 64x64 output
  int row0 = br * GBM, col0 = bc * GBN;
  int fr = lane & 15, fg = lane >> 4;

  const u16* agp[2];
  const u16* bgp[2];
  int wof[2];
  #pragma unroll
  for (int j = 0; j < 2; ++j) {
    int rr = wid * 32 + j * 16 + (lane >> 2);
    int kc = lane & 3;
    int gr = row0 + rr; if (gr >= Mrows) gr = Mrows - 1;
    agp[j] = A + (size_t)gr * 256 + kc * 8;
    bgp[j] = Bt + (size_t)(col0 + rr) * 256 + kc * 8;
    wof[j] = swz(rr * 64 + kc * 16);
  }
  int rofA[4], rofB[4];
  #pragma unroll
  for (int m = 0; m < 4; ++m) rofA[m] = swz((wr * 64 + m * 16 + fr) * 64 + fg * 16);
  #pragma unroll
  for (int n = 0; n < 4; ++n) rofB[n] = swz((wc * 64 + n * 16 + fr) * 64 + fg * 16);

  f32x4 acc[4][4];
  #pragma unroll
  for (int m = 0; m < 4; ++m)
    #pragma unroll
    for (int n = 0; n < 4; ++n) acc[m][n] = (f32x4){0.f, 0.f, 0.f, 0.f};

  uint4 va[2], vb[2];
  #pragma unroll
  for (int j = 0; j < 2; ++j) { va[j] = *(const uint4*)agp[j]; vb[j] = *(const uint4*)bgp[j]; }
  #pragma unroll
  for (int j = 0; j < 2; ++j) {
    *(uint4*)(sAc + wof[j]) = va[j];
    *(uint4*)(sBc + wof[j]) = vb[j];
  }
  __syncthreads();

  #pragma unroll
  for (int kt = 0; kt < 8; ++kt) {             // K = 8 x 32
    int buf = kt & 1;
    if (kt < 7) {                              // T14: issue next-tile loads early
      #pragma unroll
      for (int j = 0; j < 2; ++j) {
        va[j] = *(const uint4*)(agp[j] + (kt + 1) * 32);
        vb[j] = *(const uint4*)(bgp[j] + (kt + 1) * 32);
      }
    }
    short8 af[4], bf[4];
    #pragma unroll
    for (int m = 0; m < 4; ++m) af[m] = *(const short8*)(sAc + buf * 8192 + rofA[m]);
    #pragma unroll
    for (int n = 0; n < 4; ++n) bf[n] = *(const short8*)(sBc + buf * 8192 + rofB[n]);
    #pragma unroll
    for (int m = 0; m < 4; ++m)
      #pragma unroll
      for (int n = 0; n < 4; ++n)
        acc[m][n] = __builtin_amdgcn_mfma_f32_16x16x32_bf16(af[m], bf[n], acc[m][n], 0, 0, 0);
    if (kt < 7) {                              // write next buffer, one barrier
      int nb = buf ^ 1;
      #pragma unroll
      for (int j = 0; j < 2; ++j) {
        *(uint4*)(sAc + nb * 8192 + wof[j]) = va[j];
        *(uint4*)(sBc + nb * 8192 + wof[j]) = vb[j];
      }
      __syncthreads();
    }
  }

  // C write (bf16): col=lane&15 within frag, row=(lane>>4)*4+j
  #pragma unroll
  for (int m = 0; m < 4; ++m) {
    #pragma unroll
    for (int n = 0; n < 4; ++n) {
      int col = col0 + wc * 64 + n * 16 + fr;
      #pragma unroll
      for (int j = 0; j < 4; ++j) {
        int row = row0 + wr * 64 + m * 16 + fg * 4 + j;
        if (row < Mrows) C16[(size_t)row * 256 + col] = f2bf_rn(acc[m][n][j]);
      }
    }
  }

  // fused logits: this wave's 64 cols = one head
  int head = bc * 2 + wc;
  float asv[4], adv[4];
  #pragma unroll
  for (int n = 0; n < 4; ++n) {
    asv[n] = as_[head * 64 + n * 16 + fr];
    adv[n] = ad_[head * 64 + n * 16 + fr];
  }
  #pragma unroll
  for (int m = 0; m < 4; ++m) {
    #pragma unroll
    for (int j = 0; j < 4; ++j) {
      float ps = 0.f, pd = 0.f;
      #pragma unroll
      for (int n = 0; n < 4; ++n) {
        ps += acc[m][n][j] * asv[n];
        pd += acc[m][n][j] * adv[n];
      }
      #pragma unroll
      for (int off = 1; off < 16; off <<= 1) {
        ps += __shfl_xor(ps, off, 64);
        pd += __shfl_xor(pd, off, 64);
      }
      int grow = row0 + wr * 64 + m * 16 + fg * 4 + j;
      if (fr == 0 && grow < Mrows) {
        als[grow * 4 + head] = ps;
        ald[grow * 4 + head] = pd;
      }
    }
  }
}

// ---------------- edge softmax: single pass, max-free ----------------

__global__ void edge_softmax_kernel(const float* __restrict__ als, const float* __restrict__ ald,
                                    const int* __restrict__ rowptr, const int* __restrict__ col,
                                    float* __restrict__ w, float* __restrict__ invS, int Nn) {
  int node = blockIdx.x * 256 + threadIdx.x;
  if (node >= Nn) return;
  int rs = rowptr[node], re = rowptr[node + 1];
  float4 ad = *(const float4*)&ald[node * 4];
  float S0 = 0.f, S1 = 0.f, S2 = 0.f, S3 = 0.f;
  for (int i = rs; i < re; ++i) {
    int s = col[i];
    float4 a = *(const float4*)&als[(size_t)s * 4];
    float e0 = a.x + ad.x; e0 = e0 > 0.f ? e0 : NEG_SLOPE * e0;
    float e1 = a.y + ad.y; e1 = e1 > 0.f ? e1 : NEG_SLOPE * e1;
    float e2 = a.z + ad.z; e2 = e2 > 0.f ? e2 : NEG_SLOPE * e2;
    float e3 = a.w + ad.w; e3 = e3 > 0.f ? e3 : NEG_SLOPE * e3;
    float p0 = __expf(e0), p1 = __expf(e1), p2 = __expf(e2), p3 = __expf(e3);
    *(float4*)&w[(size_t)i * 4] = make_float4(p0, p1, p2, p3);
    S0 += p0; S1 += p1; S2 += p2; S3 += p3;
  }
  *(float4*)&invS[node * 4] = make_float4(1.f / (S0 + 1e-16f), 1.f / (S1 + 1e-16f),
                                          1.f / (S2 + 1e-16f), 1.f / (S3 + 1e-16f));
}

// ---------------- GAT gather v4: one dwordx2 per lane per edge ----------------
// wave per node (scalarized); lane l owns channels {4l, 4l+1, 4l+2, 4l+3},
// head = l>>4. Per edge: 1 uniform col + 1 w dword (16 lanes/address) +
// 1 dwordx2 h load (512B/wave = full row) + 4 FMA. 8B packed store.

__global__ __launch_bounds__(256) void gat_gather_kernel(const u16* __restrict__ h16,
    const float* __restrict__ w, const float* __restrict__ invS,
    const int* __restrict__ rowptr, const int* __restrict__ col,
    const float* __restrict__ bias, u16* __restrict__ out16, int Nn) {
  int node = __builtin_amdgcn_readfirstlane(blockIdx.x * 4 + (threadIdx.x >> 6));
  int lane = threadIdx.x & 63;
  if (node >= Nn) return;
  int rs = rowptr[node], re = rowptr[node + 1];
  int head = lane >> 4;                       // 16 lanes per head
  float a0 = 0.f, a1 = 0.f, a2 = 0.f, a3 = 0.f;
  const uint2* h64 = (const uint2*)h16;       // 8B units; row = 64 units
  #pragma unroll 2
  for (int i = rs; i < re; ++i) {
    int s = col[i];
    float wq = w[(size_t)i * 4 + head];
    uint2 p = h64[(size_t)s * 64 + lane];     // ch 4l..4l+3
    a0 += wq * __uint_as_float(p.x << 16);
    a1 += wq * __uint_as_float(p.x & 0xffff0000u);
    a2 += wq * __uint_as_float(p.y << 16);
    a3 += wq * __uint_as_float(p.y & 0xffff0000u);
  }
  float iS = invS[node * 4 + head];
  float4 bv = *(const float4*)&bias[4 * lane];
  float o0 = a0 * iS + bv.x;
  float o1 = a1 * iS + bv.y;
  float o2 = a2 * iS + bv.z;
  float o3 = a3 * iS + bv.w;
  o0 = o0 > 0.f ? o0 : (__expf(o0) - 1.0f);   // ELU (alpha=1)
  o1 = o1 > 0.f ? o1 : (__expf(o1) - 1.0f);
  o2 = o2 > 0.f ? o2 : (__expf(o2) - 1.0f);
  o3 = o3 > 0.f ? o3 : (__expf(o3) - 1.0f);
  uint2 ov;
  ov.x = (u32)f2bf_rn(o0) | ((u32)f2bf_rn(o1) << 16);
  ov.y = (u32)f2bf_rn(o2) | ((u32)f2bf_rn(o3) << 16);
  ((uint2*)out16)[(size_t)node * 64 + lane] = ov;
}

// ---------------- pooling + MLP ----------------

__global__ void bounds_kernel(const int* __restrict__ batch, int Nn, int* __restrict__ bounds) {
  int g = threadIdx.x;
  if (g > GG) return;
  int lo = 0, hi = Nn;
  while (lo < hi) { int mid = (lo + hi) >> 1; if (batch[mid] < g) lo = mid + 1; else hi = mid; }
  bounds[g] = lo;   // lower_bound of g; bounds[64] = N
}

// one wave per (graph, split); uint4 loads (1KB/wave-instr); lane = (rowpar, chunk)
__global__ __launch_bounds__(64) void pool_kernel(const u16* __restrict__ X,
    const int* __restrict__ bounds, float* __restrict__ pooled) {
  int g = blockIdx.x, split = blockIdx.y;
  int lane = threadIdx.x;                     // 64
  int s = bounds[g], e = bounds[g + 1];
  int cnt = e - s;
  if (cnt <= 0) return;
  int chunk = (cnt + gridDim.y - 1) / gridDim.y;
  int s2 = s + split * chunk, e2 = min(e, s2 + chunk);
  if (s2 >= e2) return;
  int r = lane >> 5, c = lane & 31;           // row parity, 16B chunk
  float acc[8] = {};
  for (int n = s2 + r; n < e2; n += 2) {
    uint4 v = *(const uint4*)&X[(size_t)n * HC + c * 8];
    acc[0] += __uint_as_float(v.x << 16);
    acc[1] += __uint_as_float(v.x & 0xffff0000u);
    acc[2] += __uint_as_float(v.y << 16);
    acc[3] += __uint_as_float(v.y & 0xffff0000u);
    acc[4] += __uint_as_float(v.z << 16);
    acc[5] += __uint_as_float(v.z & 0xffff0000u);
    acc[6] += __uint_as_float(v.w << 16);
    acc[7] += __uint_as_float(v.w & 0xffff0000u);
  }
  #pragma unroll
  for (int j = 0; j < 8; ++j) acc[j] += __shfl_xor(acc[j], 32, 64);
  if (r == 0) {
    #pragma unroll
    for (int j = 0; j < 8; ++j) atomicAdd(&pooled[g * HC + c * 8 + j], acc[j]);
  }
}

__global__ __launch_bounds__(512) void mlp_kernel(const float* __restrict__ pooled,
    const int* __restrict__ bounds, const float* __restrict__ Wp1, const float* __restrict__ bp1,
    const float* __restrict__ Wp2, const float* __restrict__ bp2, float* __restrict__ out) {
  __shared__ float p[256];
  __shared__ float z1[512];
  int g = blockIdx.x, t = threadIdx.x;
  if (t < 256) {
    int cnt = bounds[g + 1] - bounds[g];
    float inv = 1.0f / (float)(cnt > 1 ? cnt : 1);
    p[t] = pooled[g * 256 + t] * inv;
  }
  __syncthreads();
  float a1 = bp1[t];
  for (int k = 0; k < 256; ++k) a1 += p[k] * Wp1[k * 512 + t];
  z1[t] = fmaxf(a1, 0.f);
  __syncthreads();
  if (t < 256) {
    float a2 = bp2[t];
    for (int k = 0; k < 512; ++k) a2 += z1[k] * Wp2[k * 256 + t];
    out[g * 256 + t] = a2;
  }
}

// ---------------- launch ----------------

static inline size_t align_up(size_t x, size_t a) { return (x + a - 1) & ~(a - 1); }

extern "C" void kernel_launch(void* const* d_in, const int* in_sizes, int n_in,
                              void* d_out, int out_size, void* d_ws, size_t ws_size,
                              hipStream_t stream) {
  const float* x    = (const float*)d_in[0];
  const int*   ei   = (const int*)d_in[1];
  const int*   batch= (const int*)d_in[2];
  const float* W1   = (const float*)d_in[3];
  const float* a1s  = (const float*)d_in[4];
  const float* a1d  = (const float*)d_in[5];
  const float* b1   = (const float*)d_in[6];
  const float* W2   = (const float*)d_in[7];
  const float* a2s  = (const float*)d_in[8];
  const float* a2d  = (const float*)d_in[9];
  const float* b2   = (const float*)d_in[10];
  const float* W3   = (const float*)d_in[11];
  const float* a3s  = (const float*)d_in[12];
  const float* a3d  = (const float*)d_in[13];
  const float* b3   = (const float*)d_in[14];
  const float* Wp1  = (const float*)d_in[15];
  const float* bp1  = (const float*)d_in[16];
  const float* Wp2  = (const float*)d_in[17];
  const float* bp2  = (const float*)d_in[18];

  const int N = in_sizes[0] / 2;       // 100000
  const int E = in_sizes[1] / 2;       // 400000
  const int Et = E + N;                // with self loops

  char* base = (char*)d_ws;
  size_t off = 0;
  auto alloc = [&](size_t bytes) { size_t o = off; off = align_up(off + bytes, 256); return o; };
  u16*   h16    = (u16*)  (base + alloc((size_t)N * HC * 2));   // message-path h (bf16)
  u16*   xhi    = (u16*)  (base + alloc((size_t)N * HC * 2));   // gather out (bf16)
  float* als    = (float*)(base + alloc((size_t)N * 4 * 4));
  float* ald    = (float*)(base + alloc((size_t)N * 4 * 4));
  float* invS   = (float*)(base + alloc((size_t)N * 4 * 4));
  float* xbar   = (float*)(base + alloc((size_t)N * 8 * 4));    // layer-1 x-space gather
  float* vabuf  = (float*)(base + alloc(16 * 4));
  int*   rowptr = (int*)  (base + alloc((size_t)(N + 1) * 4));
  int*   col    = (int*)  (base + alloc((size_t)Et * 4));
  float* w      = (float*)(base + alloc((size_t)Et * 4 * 4));   // per-edge softmax numerators
  int*   deg    = (int*)  (base + alloc((size_t)N * 4));
  int*   cursor = (int*)  (base + alloc((size_t)N * 4));
  int*   bsum   = (int*)  (base + alloc(512 * 4));
  int*   bounds = (int*)  (base + alloc((GG + 1) * 4));
  float* pooled = (float*)(base + alloc((size_t)GG * HC * 4));
  (void)ws_size; (void)n_in; (void)out_size;

  // W2t/W3t (bf16, 128KB each) parked in deg/cursor space (dead after CSR build)
  u16* W2t = (u16*)deg;
  u16* W3t = (u16*)cursor;

  hipMemsetAsync(deg, 0, (size_t)N * 4, stream);
  hipMemsetAsync(cursor, 0, (size_t)N * 4, stream);
  hipMemsetAsync(pooled, 0, (size_t)GG * HC * 4, stream);

  // CSR by destination (same edge set for all layers)
  int ebk = (Et + 255) / 256;
  count_deg_kernel<<<ebk, 256, 0, stream>>>(ei, E, N, deg);
  int NT = (N + 255) / 256;
  scan_partial_kernel<<<NT, 256, 0, stream>>>(deg, N, rowptr, bsum);
  scan_bsum_kernel<<<1, 512, 0, stream>>>(bsum, NT);
  scan_add_kernel<<<NT, 256, 0, stream>>>(rowptr, bsum, N, Et);
  fill_csr_kernel<<<ebk, 256, 0, stream>>>(ei, E, N, rowptr, cursor, col);

  // weight conversion (deg/cursor now dead)
  convert_w_kernel<<<256, 256, 0, stream>>>(W2, W2t);
  convert_w_kernel<<<256, 256, 0, stream>>>(W3, W3t);

  dim3 gemm_grid(HC / GBN, (N + GBM - 1) / GBM);
  int nodeblk = (N + 3) / 4;

  // layer 1 — rank-2 factorization: everything in x-space, then one expand
  prep_va_kernel<<<1, 256, 0, stream>>>(W1, a1s, a1d, vabuf);
  logits1_kernel<<<NT, 256, 0, stream>>>(x, vabuf, als, ald, N);
  sm_gather1_kernel<<<NT, 256, 0, stream>>>(x, als, ald, rowptr, col, xbar, N);
  expand1_kernel<<<nodeblk, 256, 0, stream>>>(xbar, W1, b1, xhi, N);
  // layer 2
  gemm_mfma_kernel<<<gemm_grid, 256, 0, stream>>>(xhi, W2t, a2s, a2d, h16, als, ald, N);
  edge_softmax_kernel<<<NT, 256, 0, stream>>>(als, ald, rowptr, col, w, invS, N);
  gat_gather_kernel<<<nodeblk, 256, 0, stream>>>(h16, w, invS, rowptr, col, b2, xhi, N);
  // layer 3
  gemm_mfma_kernel<<<gemm_grid, 256, 0, stream>>>(xhi, W3t, a3s, a3d, h16, als, ald, N);
  edge_softmax_kernel<<<NT, 256, 0, stream>>>(als, ald, rowptr, col, w, invS, N);
  gat_gather_kernel<<<nodeblk, 256, 0, stream>>>(h16, w, invS, rowptr, col, b3, xhi, N);

  // pool + MLP
  bounds_kernel<<<1, 128, 0, stream>>>(batch, N, bounds);
  pool_kernel<<<dim3(GG, 32), 64, 0, stream>>>(xhi, bounds, pooled);
  mlp_kernel<<<GG, 512, 0, stream>>>(pooled, bounds, Wp1, bp1, Wp2, bp2, (float*)d_out);
}